// Round 1
// baseline (2271.182 us; speedup 1.0000x reference)
//
#include <hip/hip_runtime.h>

#define NNODES 100000
#define NEDGES 3200000
#define NF 13
#define NH 64
#define NG 512
#define BN_EPS 1e-5f

// ---------------- scatter-add over edges, FIN=13 (thread per edge*feature) -------------
__global__ void scatter_small_kernel(const float* __restrict__ x,
                                     const int* __restrict__ src,
                                     const int* __restrict__ dst,
                                     float* __restrict__ agg) {
    const int total = NEDGES * NF;
    int idx = blockIdx.x * blockDim.x + threadIdx.x;
    int stride = gridDim.x * blockDim.x;
    for (; idx < total; idx += stride) {
        int e = idx / NF;
        int f = idx - e * NF;
        atomicAdd(&agg[dst[e] * NF + f], x[src[e] * NF + f]);
    }
}

// ---------------- scatter-add over edges, FIN=64 (wave per edge, lane=feature) ---------
__global__ void scatter64_kernel(const float* __restrict__ h,
                                 const int* __restrict__ src,
                                 const int* __restrict__ dst,
                                 float* __restrict__ agg) {
    int wave = (blockIdx.x * blockDim.x + threadIdx.x) >> 6;
    int lane = threadIdx.x & 63;
    int nw = (gridDim.x * blockDim.x) >> 6;
    for (int e = wave; e < NEDGES; e += nw) {
        int s = src[e], d = dst[e];
        atomicAdd(&agg[d * 64 + lane], h[s * 64 + lane]);
    }
}

// ---------------- fused GIN MLP: h = relu(relu(BN((x+agg)@W1+b1))@W2+b2), + pooling ----
// One wave per node; lane = output feature. W1,W2 staged in LDS; cross-lane via shfl.
template <int FIN>
__launch_bounds__(256)
__global__ void gin_mlp_kernel(const float* __restrict__ xin,
                               const float* __restrict__ agg,
                               const float* __restrict__ W1, const float* __restrict__ b1,
                               const float* __restrict__ g,  const float* __restrict__ be,
                               const float* __restrict__ m,  const float* __restrict__ v,
                               const float* __restrict__ W2, const float* __restrict__ b2,
                               float* __restrict__ hout,
                               float* __restrict__ pool, const int* __restrict__ batch,
                               int poolOff) {
    __shared__ float W1s[FIN * 64];
    __shared__ float W2s[64 * 64];
    for (int i = threadIdx.x; i < FIN * 64; i += 256) W1s[i] = W1[i];
    for (int i = threadIdx.x; i < 64 * 64; i += 256) W2s[i] = W2[i];
    __syncthreads();

    int lane = threadIdx.x & 63;
    int wave = (blockIdx.x * blockDim.x + threadIdx.x) >> 6;
    int nw = (gridDim.x * blockDim.x) >> 6;

    // fold BN: z = (acc + b1 - m) * g/sqrt(v+eps) + be
    float scale = g[lane] * rsqrtf(v[lane] + BN_EPS);
    float shift = be[lane] - m[lane] * scale;
    float bb1 = b1[lane];
    float bb2 = b2[lane];

    for (int n = wave; n < NNODES; n += nw) {
        float y = 0.f;
        if (lane < FIN) y = xin[n * FIN + lane] + agg[n * FIN + lane];
        float acc = 0.f;
#pragma unroll
        for (int k = 0; k < FIN; ++k) {
            float yk = __shfl(y, k, 64);
            acc = fmaf(yk, W1s[k * 64 + lane], acc);
        }
        float z = fmaxf(fmaf(acc + bb1, scale, shift), 0.f);
        float acc2 = 0.f;
#pragma unroll
        for (int k = 0; k < 64; ++k) {
            float zk = __shfl(z, k, 64);
            acc2 = fmaf(zk, W2s[k * 64 + lane], acc2);
        }
        float h = fmaxf(acc2 + bb2, 0.f);
        hout[n * 64 + lane] = h;
        atomicAdd(&pool[batch[n] * 192 + poolOff + lane], h);
    }
}

// ---------------- FC head: relu(p@fc1W+fc1b) @ fc2W + fc2b, log_softmax --------------
__global__ void final_kernel(const float* __restrict__ pool,
                             const float* __restrict__ fc1W, const float* __restrict__ fc1b,
                             const float* __restrict__ fc2W, const float* __restrict__ fc2b,
                             float* __restrict__ out) {
    __shared__ float ps[192];
    __shared__ float hs[192];
    int gi = blockIdx.x;
    int t = threadIdx.x;  // 192
    ps[t] = pool[gi * 192 + t];
    __syncthreads();
    float acc = fc1b[t];
#pragma unroll 8
    for (int k = 0; k < 192; ++k) acc = fmaf(ps[k], fc1W[k * 192 + t], acc);
    hs[t] = fmaxf(acc, 0.f);
    __syncthreads();
    if (t == 0) {
        float l0 = fc2b[0], l1 = fc2b[1];
        for (int k = 0; k < 192; ++k) {
            float h = hs[k];
            l0 = fmaf(h, fc2W[k * 2 + 0], l0);
            l1 = fmaf(h, fc2W[k * 2 + 1], l1);
        }
        float mx = fmaxf(l0, l1);
        float lse = mx + logf(expf(l0 - mx) + expf(l1 - mx));
        out[gi * 2 + 0] = l0 - lse;
        out[gi * 2 + 1] = l1 - lse;
    }
}

extern "C" void kernel_launch(void* const* d_in, const int* in_sizes, int n_in,
                              void* d_out, int out_size, void* d_ws, size_t ws_size,
                              hipStream_t stream) {
    const float* x = (const float*)d_in[0];
    const int* src = (const int*)d_in[1];
    const int* dst = (const int*)d_in[2];
    const int* batch = (const int*)d_in[3];
    const float* c1[8];
    const float* c2[8];
    const float* c3[8];
    for (int i = 0; i < 8; ++i) {
        c1[i] = (const float*)d_in[4 + i];
        c2[i] = (const float*)d_in[12 + i];
        c3[i] = (const float*)d_in[20 + i];
    }
    const float* fc1W = (const float*)d_in[28];
    const float* fc1b = (const float*)d_in[29];
    const float* fc2W = (const float*)d_in[30];
    const float* fc2b = (const float*)d_in[31];
    float* out = (float*)d_out;

    float* ws = (float*)d_ws;
    const size_t NA = (size_t)NNODES * 64;
    float* agg  = ws;            // N*64 (layer1 uses N*13)
    float* bufA = ws + NA;       // h1, then h3
    float* bufB = ws + 2 * NA;   // h2
    float* pool = ws + 3 * NA;   // G*192

    hipMemsetAsync(pool, 0, (size_t)NG * 192 * sizeof(float), stream);

    // Layer 1 (fin=13)
    hipMemsetAsync(agg, 0, (size_t)NNODES * NF * sizeof(float), stream);
    scatter_small_kernel<<<2048, 256, 0, stream>>>(x, src, dst, agg);
    gin_mlp_kernel<NF><<<2048, 256, 0, stream>>>(
        x, agg, c1[0], c1[1], c1[2], c1[3], c1[4], c1[5], c1[6], c1[7],
        bufA, pool, batch, 0);

    // Layer 2 (fin=64)
    hipMemsetAsync(agg, 0, NA * sizeof(float), stream);
    scatter64_kernel<<<2048, 256, 0, stream>>>(bufA, src, dst, agg);
    gin_mlp_kernel<NH><<<2048, 256, 0, stream>>>(
        bufA, agg, c2[0], c2[1], c2[2], c2[3], c2[4], c2[5], c2[6], c2[7],
        bufB, pool, batch, 64);

    // Layer 3 (fin=64)
    hipMemsetAsync(agg, 0, NA * sizeof(float), stream);
    scatter64_kernel<<<2048, 256, 0, stream>>>(bufB, src, dst, agg);
    gin_mlp_kernel<NH><<<2048, 256, 0, stream>>>(
        bufB, agg, c3[0], c3[1], c3[2], c3[3], c3[4], c3[5], c3[6], c3[7],
        bufA, pool, batch, 128);

    final_kernel<<<NG, 192, 0, stream>>>(pool, fc1W, fc1b, fc2W, fc2b, out);
}

// Round 2
// 1622.095 us; speedup vs baseline: 1.4002x; 1.4002x over previous
//
#include <hip/hip_runtime.h>

#define NNODES 100000
#define NEDGES 3200000
#define NF 13
#define NG 512
#define BN_EPS 1e-5f

#define SCAN_BLK 256
#define NBLK ((NNODES + SCAN_BLK - 1) / SCAN_BLK)   // 391

// ---------------- CSR build: histogram of dst ----------------
__global__ void hist_kernel(const int* __restrict__ dst, int* __restrict__ deg) {
    int idx = blockIdx.x * blockDim.x + threadIdx.x;
    int stride = gridDim.x * blockDim.x;
    for (int e = idx; e < NEDGES; e += stride) atomicAdd(&deg[dst[e]], 1);
}

// ---------------- per-block partial sums of deg ----------------
__global__ void partial_sum_kernel(const int* __restrict__ deg, int* __restrict__ partials) {
    __shared__ int s[SCAN_BLK];
    int t = threadIdx.x;
    int i = blockIdx.x * SCAN_BLK + t;
    s[t] = (i < NNODES) ? deg[i] : 0;
    __syncthreads();
    for (int off = SCAN_BLK / 2; off > 0; off >>= 1) {
        if (t < off) s[t] += s[t + off];
        __syncthreads();
    }
    if (t == 0) partials[blockIdx.x] = s[0];
}

// ---------------- exclusive scan of partials (single block, 512 >= NBLK) --------------
__global__ void scan_partials_kernel(int* __restrict__ partials) {
    __shared__ int s[512];
    int t = threadIdx.x;
    int v = (t < NBLK) ? partials[t] : 0;
    s[t] = v;
    __syncthreads();
    for (int off = 1; off < 512; off <<= 1) {
        int tmp = (t >= off) ? s[t - off] : 0;
        __syncthreads();
        s[t] += tmp;
        __syncthreads();
    }
    if (t < NBLK) partials[t] = s[t] - v;  // exclusive
}

// ---------------- per-block exclusive scan -> offsets, cursor ----------------
__global__ void scan_block_kernel(const int* __restrict__ deg, const int* __restrict__ partials,
                                  int* __restrict__ offsets, int* __restrict__ cursor) {
    __shared__ int s[SCAN_BLK];
    int t = threadIdx.x;
    int i = blockIdx.x * SCAN_BLK + t;
    int v = (i < NNODES) ? deg[i] : 0;
    s[t] = v;
    __syncthreads();
    for (int off = 1; off < SCAN_BLK; off <<= 1) {
        int tmp = (t >= off) ? s[t - off] : 0;
        __syncthreads();
        s[t] += tmp;
        __syncthreads();
    }
    if (i < NNODES) {
        int excl = partials[blockIdx.x] + s[t] - v;
        offsets[i] = excl;
        cursor[i] = excl;
    }
    if (i == 0) offsets[NNODES] = NEDGES;
}

// ---------------- scatter edges into CSR slots ----------------
__global__ void build_csr_kernel(const int* __restrict__ src, const int* __restrict__ dst,
                                 int* __restrict__ cursor, int* __restrict__ csr) {
    int idx = blockIdx.x * blockDim.x + threadIdx.x;
    int stride = gridDim.x * blockDim.x;
    for (int e = idx; e < NEDGES; e += stride) {
        int pos = atomicAdd(&cursor[dst[e]], 1);
        csr[pos] = src[e];
    }
}

// ---------------- fused gather + GIN MLP + pooling ----------------
// One wave per node; lane = feature. Gather in-neighbor rows (no atomics),
// y = x[n] + sum_j x[src_j]; then relu(relu(BN(y@W1+b1))@W2+b2); pool atomic.
template <int FIN>
__launch_bounds__(256)
__global__ void gin_fused_kernel(const float* __restrict__ xin,
                                 const int* __restrict__ offsets,
                                 const int* __restrict__ csr,
                                 const float* __restrict__ W1, const float* __restrict__ b1,
                                 const float* __restrict__ g,  const float* __restrict__ be,
                                 const float* __restrict__ m,  const float* __restrict__ v,
                                 const float* __restrict__ W2, const float* __restrict__ b2,
                                 float* __restrict__ hout,
                                 float* __restrict__ pool, const int* __restrict__ batch,
                                 int poolOff) {
    __shared__ float W1s[FIN * 64];
    __shared__ float W2s[64 * 64];
    for (int i = threadIdx.x; i < FIN * 64; i += 256) W1s[i] = W1[i];
    for (int i = threadIdx.x; i < 64 * 64; i += 256) W2s[i] = W2[i];
    __syncthreads();

    int lane = threadIdx.x & 63;
    int wave = (blockIdx.x * blockDim.x + threadIdx.x) >> 6;
    int nw = (gridDim.x * blockDim.x) >> 6;

    float scale = g[lane] * rsqrtf(v[lane] + BN_EPS);
    float shift = be[lane] - m[lane] * scale;
    float bb1 = b1[lane];
    float bb2 = b2[lane];

    for (int n = wave; n < NNODES; n += nw) {
        int beg = offsets[n];
        int end = offsets[n + 1];
        float y = 0.f;
        if (lane < FIN) y = xin[n * FIN + lane];
        int j = beg;
        for (; j + 4 <= end; j += 4) {
            int s0 = csr[j], s1 = csr[j + 1], s2 = csr[j + 2], s3 = csr[j + 3];
            float a0 = 0.f, a1 = 0.f, a2 = 0.f, a3 = 0.f;
            if (lane < FIN) {
                a0 = xin[s0 * FIN + lane];
                a1 = xin[s1 * FIN + lane];
                a2 = xin[s2 * FIN + lane];
                a3 = xin[s3 * FIN + lane];
            }
            y += (a0 + a1) + (a2 + a3);
        }
        for (; j < end; ++j) {
            int s0 = csr[j];
            if (lane < FIN) y += xin[s0 * FIN + lane];
        }

        float acc = 0.f;
#pragma unroll
        for (int k = 0; k < FIN; ++k) {
            float yk = __shfl(y, k, 64);
            acc = fmaf(yk, W1s[k * 64 + lane], acc);
        }
        float z = fmaxf(fmaf(acc + bb1, scale, shift), 0.f);
        float acc2 = 0.f;
#pragma unroll
        for (int k = 0; k < 64; ++k) {
            float zk = __shfl(z, k, 64);
            acc2 = fmaf(zk, W2s[k * 64 + lane], acc2);
        }
        float h = fmaxf(acc2 + bb2, 0.f);
        hout[n * 64 + lane] = h;
        atomicAdd(&pool[batch[n] * 192 + poolOff + lane], h);
    }
}

// ---------------- FC head: relu(p@fc1W+fc1b) @ fc2W + fc2b, log_softmax --------------
__global__ void final_kernel(const float* __restrict__ pool,
                             const float* __restrict__ fc1W, const float* __restrict__ fc1b,
                             const float* __restrict__ fc2W, const float* __restrict__ fc2b,
                             float* __restrict__ out) {
    __shared__ float ps[192];
    __shared__ float hs[192];
    int gi = blockIdx.x;
    int t = threadIdx.x;  // 192
    ps[t] = pool[gi * 192 + t];
    __syncthreads();
    float acc = fc1b[t];
#pragma unroll 8
    for (int k = 0; k < 192; ++k) acc = fmaf(ps[k], fc1W[k * 192 + t], acc);
    hs[t] = fmaxf(acc, 0.f);
    __syncthreads();
    if (t == 0) {
        float l0 = fc2b[0], l1 = fc2b[1];
        for (int k = 0; k < 192; ++k) {
            float h = hs[k];
            l0 = fmaf(h, fc2W[k * 2 + 0], l0);
            l1 = fmaf(h, fc2W[k * 2 + 1], l1);
        }
        float mx = fmaxf(l0, l1);
        float lse = mx + logf(expf(l0 - mx) + expf(l1 - mx));
        out[gi * 2 + 0] = l0 - lse;
        out[gi * 2 + 1] = l1 - lse;
    }
}

extern "C" void kernel_launch(void* const* d_in, const int* in_sizes, int n_in,
                              void* d_out, int out_size, void* d_ws, size_t ws_size,
                              hipStream_t stream) {
    const float* x = (const float*)d_in[0];
    const int* src = (const int*)d_in[1];
    const int* dst = (const int*)d_in[2];
    const int* batch = (const int*)d_in[3];
    const float* c1[8];
    const float* c2[8];
    const float* c3[8];
    for (int i = 0; i < 8; ++i) {
        c1[i] = (const float*)d_in[4 + i];
        c2[i] = (const float*)d_in[12 + i];
        c3[i] = (const float*)d_in[20 + i];
    }
    const float* fc1W = (const float*)d_in[28];
    const float* fc1b = (const float*)d_in[29];
    const float* fc2W = (const float*)d_in[30];
    const float* fc2b = (const float*)d_in[31];
    float* out = (float*)d_out;

    // ---- workspace layout: float buffers first (16B aligned), ints after ----
    float* ws = (float*)d_ws;
    const size_t NA = (size_t)NNODES * 64;
    float* bufA = ws;                 // h1, then h3
    float* bufB = ws + NA;            // h2
    float* pool = ws + 2 * NA;        // G*192
    int* ibase  = (int*)(ws + 2 * NA + (size_t)NG * 192);
    int* deg     = ibase;                     // N (reused scratch)
    int* offsets = ibase + NNODES;            // N+1
    int* cursor  = offsets + NNODES + 1;      // N
    int* csr     = cursor + NNODES;           // E
    int* partials = csr + NEDGES;             // NBLK

    hipMemsetAsync(pool, 0, (size_t)NG * 192 * sizeof(float), stream);
    hipMemsetAsync(deg, 0, (size_t)NNODES * sizeof(int), stream);

    // ---- build CSR by dst (once; reused by all 3 layers) ----
    hist_kernel<<<1024, 256, 0, stream>>>(dst, deg);
    partial_sum_kernel<<<NBLK, SCAN_BLK, 0, stream>>>(deg, partials);
    scan_partials_kernel<<<1, 512, 0, stream>>>(partials);
    scan_block_kernel<<<NBLK, SCAN_BLK, 0, stream>>>(deg, partials, offsets, cursor);
    build_csr_kernel<<<2048, 256, 0, stream>>>(src, dst, cursor, csr);

    // ---- layer 1 (fin=13) ----
    gin_fused_kernel<NF><<<2048, 256, 0, stream>>>(
        x, offsets, csr, c1[0], c1[1], c1[2], c1[3], c1[4], c1[5], c1[6], c1[7],
        bufA, pool, batch, 0);
    // ---- layer 2 (fin=64) ----
    gin_fused_kernel<64><<<2048, 256, 0, stream>>>(
        bufA, offsets, csr, c2[0], c2[1], c2[2], c2[3], c2[4], c2[5], c2[6], c2[7],
        bufB, pool, batch, 64);
    // ---- layer 3 (fin=64) ----
    gin_fused_kernel<64><<<2048, 256, 0, stream>>>(
        bufB, offsets, csr, c3[0], c3[1], c3[2], c3[3], c3[4], c3[5], c3[6], c3[7],
        bufA, pool, batch, 128);

    final_kernel<<<NG, 192, 0, stream>>>(pool, fc1W, fc1b, fc2W, fc2b, out);
}

// Round 3
// 1337.104 us; speedup vs baseline: 1.6986x; 1.2131x over previous
//
#include <hip/hip_runtime.h>

#define NNODES 100000
#define NEDGES 3200000
#define NF 13
#define NG 512
#define BN_EPS 1e-5f

#define SCAN_BLK 256
#define NBLK ((NNODES + SCAN_BLK - 1) / SCAN_BLK)   // 391

// ---------------- CSR build: histogram of dst ----------------
__global__ void hist_kernel(const int* __restrict__ dst, int* __restrict__ deg) {
    int idx = blockIdx.x * blockDim.x + threadIdx.x;
    int stride = gridDim.x * blockDim.x;
    for (int e = idx; e < NEDGES; e += stride) atomicAdd(&deg[dst[e]], 1);
}

// ---------------- per-block partial sums of deg ----------------
__global__ void partial_sum_kernel(const int* __restrict__ deg, int* __restrict__ partials) {
    __shared__ int s[SCAN_BLK];
    int t = threadIdx.x;
    int i = blockIdx.x * SCAN_BLK + t;
    s[t] = (i < NNODES) ? deg[i] : 0;
    __syncthreads();
    for (int off = SCAN_BLK / 2; off > 0; off >>= 1) {
        if (t < off) s[t] += s[t + off];
        __syncthreads();
    }
    if (t == 0) partials[blockIdx.x] = s[0];
}

// ---------------- exclusive scan of partials (single block, 512 >= NBLK) --------------
__global__ void scan_partials_kernel(int* __restrict__ partials) {
    __shared__ int s[512];
    int t = threadIdx.x;
    int v = (t < NBLK) ? partials[t] : 0;
    s[t] = v;
    __syncthreads();
    for (int off = 1; off < 512; off <<= 1) {
        int tmp = (t >= off) ? s[t - off] : 0;
        __syncthreads();
        s[t] += tmp;
        __syncthreads();
    }
    if (t < NBLK) partials[t] = s[t] - v;  // exclusive
}

// ---------------- per-block exclusive scan -> offsets, cursor ----------------
__global__ void scan_block_kernel(const int* __restrict__ deg, const int* __restrict__ partials,
                                  int* __restrict__ offsets, int* __restrict__ cursor) {
    __shared__ int s[SCAN_BLK];
    int t = threadIdx.x;
    int i = blockIdx.x * SCAN_BLK + t;
    int v = (i < NNODES) ? deg[i] : 0;
    s[t] = v;
    __syncthreads();
    for (int off = 1; off < SCAN_BLK; off <<= 1) {
        int tmp = (t >= off) ? s[t - off] : 0;
        __syncthreads();
        s[t] += tmp;
        __syncthreads();
    }
    if (i < NNODES) {
        int excl = partials[blockIdx.x] + s[t] - v;
        offsets[i] = excl;
        cursor[i] = excl;
    }
    if (i == 0) offsets[NNODES] = NEDGES;
}

// ---------------- scatter edges into CSR slots ----------------
__global__ void build_csr_kernel(const int* __restrict__ src, const int* __restrict__ dst,
                                 int* __restrict__ cursor, int* __restrict__ csr) {
    int idx = blockIdx.x * blockDim.x + threadIdx.x;
    int stride = gridDim.x * blockDim.x;
    for (int e = idx; e < NEDGES; e += stride) {
        int pos = atomicAdd(&cursor[dst[e]], 1);
        csr[pos] = src[e];
    }
}

// ---------------- lean aggregation: y[n] = x[n] + sum_{j in N(n)} x[j] -----------------
// One wave per node, lane = feature. No LDS, low VGPR -> 8 waves/SIMD for latency hiding.
// Output always stride 64 (layer-1 rows padded; lanes >= FIN unwritten/unread).
template <int FIN>
__launch_bounds__(256, 8)
__global__ void agg_kernel(const float* __restrict__ xin,
                           const int* __restrict__ offsets,
                           const int* __restrict__ csr,
                           float* __restrict__ y) {
    int lane = threadIdx.x & 63;
    int wave = (blockIdx.x * blockDim.x + threadIdx.x) >> 6;
    int nw = (gridDim.x * blockDim.x) >> 6;
    for (int n = wave; n < NNODES; n += nw) {
        int beg = offsets[n], end = offsets[n + 1];
        float acc = 0.f;
        if (FIN == 64) acc = xin[n * 64 + lane];
        else if (lane < FIN) acc = xin[n * FIN + lane];
        int j = beg;
        for (; j + 8 <= end; j += 8) {
            // wave-uniform index loads (broadcast, 1 cache line), then 8 in-flight gathers
            int s0 = csr[j + 0], s1 = csr[j + 1], s2 = csr[j + 2], s3 = csr[j + 3];
            int s4 = csr[j + 4], s5 = csr[j + 5], s6 = csr[j + 6], s7 = csr[j + 7];
            float a0 = 0.f, a1 = 0.f, a2 = 0.f, a3 = 0.f;
            float a4 = 0.f, a5 = 0.f, a6 = 0.f, a7 = 0.f;
            if (FIN == 64) {
                a0 = xin[s0 * 64 + lane]; a1 = xin[s1 * 64 + lane];
                a2 = xin[s2 * 64 + lane]; a3 = xin[s3 * 64 + lane];
                a4 = xin[s4 * 64 + lane]; a5 = xin[s5 * 64 + lane];
                a6 = xin[s6 * 64 + lane]; a7 = xin[s7 * 64 + lane];
            } else if (lane < FIN) {
                a0 = xin[s0 * FIN + lane]; a1 = xin[s1 * FIN + lane];
                a2 = xin[s2 * FIN + lane]; a3 = xin[s3 * FIN + lane];
                a4 = xin[s4 * FIN + lane]; a5 = xin[s5 * FIN + lane];
                a6 = xin[s6 * FIN + lane]; a7 = xin[s7 * FIN + lane];
            }
            acc += ((a0 + a1) + (a2 + a3)) + ((a4 + a5) + (a6 + a7));
        }
        for (; j < end; ++j) {
            int s0 = csr[j];
            if (FIN == 64) acc += xin[s0 * 64 + lane];
            else if (lane < FIN) acc += xin[s0 * FIN + lane];
        }
        if (FIN == 64 || lane < FIN) y[n * 64 + lane] = acc;
    }
}

// ---------------- MLP (in place): row = relu(relu(BN(row@W1+b1))@W2+b2), + pooling ----
// One wave per node; reads its y row (stride 64, lanes < FIN), writes h to the same row.
template <int FIN>
__launch_bounds__(256)
__global__ void mlp_kernel(float* __restrict__ buf,
                           const float* __restrict__ W1, const float* __restrict__ b1,
                           const float* __restrict__ g,  const float* __restrict__ be,
                           const float* __restrict__ m,  const float* __restrict__ v,
                           const float* __restrict__ W2, const float* __restrict__ b2,
                           float* __restrict__ pool, const int* __restrict__ batch,
                           int poolOff) {
    __shared__ float W1s[FIN * 64];
    __shared__ float W2s[64 * 64];
    for (int i = threadIdx.x; i < FIN * 64; i += 256) W1s[i] = W1[i];
    for (int i = threadIdx.x; i < 64 * 64; i += 256) W2s[i] = W2[i];
    __syncthreads();

    int lane = threadIdx.x & 63;
    int wave = (blockIdx.x * blockDim.x + threadIdx.x) >> 6;
    int nw = (gridDim.x * blockDim.x) >> 6;

    float scale = g[lane] * rsqrtf(v[lane] + BN_EPS);
    float shift = be[lane] - m[lane] * scale;
    float bb1 = b1[lane];
    float bb2 = b2[lane];

    for (int n = wave; n < NNODES; n += nw) {
        float y = 0.f;
        if (lane < FIN) y = buf[n * 64 + lane];
        float acc = 0.f;
#pragma unroll
        for (int k = 0; k < FIN; ++k) {
            float yk = __shfl(y, k, 64);
            acc = fmaf(yk, W1s[k * 64 + lane], acc);
        }
        float z = fmaxf(fmaf(acc + bb1, scale, shift), 0.f);
        float acc2 = 0.f;
#pragma unroll
        for (int k = 0; k < 64; ++k) {
            float zk = __shfl(z, k, 64);
            acc2 = fmaf(zk, W2s[k * 64 + lane], acc2);
        }
        float h = fmaxf(acc2 + bb2, 0.f);
        buf[n * 64 + lane] = h;
        atomicAdd(&pool[batch[n] * 192 + poolOff + lane], h);
    }
}

// ---------------- FC head: relu(p@fc1W+fc1b) @ fc2W + fc2b, log_softmax --------------
__global__ void final_kernel(const float* __restrict__ pool,
                             const float* __restrict__ fc1W, const float* __restrict__ fc1b,
                             const float* __restrict__ fc2W, const float* __restrict__ fc2b,
                             float* __restrict__ out) {
    __shared__ float ps[192];
    __shared__ float hs[192];
    int gi = blockIdx.x;
    int t = threadIdx.x;  // 192
    ps[t] = pool[gi * 192 + t];
    __syncthreads();
    float acc = fc1b[t];
#pragma unroll 8
    for (int k = 0; k < 192; ++k) acc = fmaf(ps[k], fc1W[k * 192 + t], acc);
    hs[t] = fmaxf(acc, 0.f);
    __syncthreads();
    if (t == 0) {
        float l0 = fc2b[0], l1 = fc2b[1];
        for (int k = 0; k < 192; ++k) {
            float h = hs[k];
            l0 = fmaf(h, fc2W[k * 2 + 0], l0);
            l1 = fmaf(h, fc2W[k * 2 + 1], l1);
        }
        float mx = fmaxf(l0, l1);
        float lse = mx + logf(expf(l0 - mx) + expf(l1 - mx));
        out[gi * 2 + 0] = l0 - lse;
        out[gi * 2 + 1] = l1 - lse;
    }
}

extern "C" void kernel_launch(void* const* d_in, const int* in_sizes, int n_in,
                              void* d_out, int out_size, void* d_ws, size_t ws_size,
                              hipStream_t stream) {
    const float* x = (const float*)d_in[0];
    const int* src = (const int*)d_in[1];
    const int* dst = (const int*)d_in[2];
    const int* batch = (const int*)d_in[3];
    const float* c1[8];
    const float* c2[8];
    const float* c3[8];
    for (int i = 0; i < 8; ++i) {
        c1[i] = (const float*)d_in[4 + i];
        c2[i] = (const float*)d_in[12 + i];
        c3[i] = (const float*)d_in[20 + i];
    }
    const float* fc1W = (const float*)d_in[28];
    const float* fc1b = (const float*)d_in[29];
    const float* fc2W = (const float*)d_in[30];
    const float* fc2b = (const float*)d_in[31];
    float* out = (float*)d_out;

    // ---- workspace layout ----
    float* ws = (float*)d_ws;
    const size_t NA = (size_t)NNODES * 64;
    float* bufA = ws;                 // y1/h1, then y3/h3
    float* bufB = ws + NA;            // y2/h2
    float* pool = ws + 2 * NA;        // G*192
    int* ibase  = (int*)(ws + 2 * NA + (size_t)NG * 192);
    int* deg      = ibase;                    // N
    int* offsets  = ibase + NNODES;           // N+1
    int* cursor   = offsets + NNODES + 1;     // N
    int* csr      = cursor + NNODES;          // E
    int* partials = csr + NEDGES;             // NBLK

    hipMemsetAsync(pool, 0, (size_t)NG * 192 * sizeof(float), stream);
    hipMemsetAsync(deg, 0, (size_t)NNODES * sizeof(int), stream);

    // ---- build CSR by dst (once; reused by all 3 layers) ----
    hist_kernel<<<1024, 256, 0, stream>>>(dst, deg);
    partial_sum_kernel<<<NBLK, SCAN_BLK, 0, stream>>>(deg, partials);
    scan_partials_kernel<<<1, 512, 0, stream>>>(partials);
    scan_block_kernel<<<NBLK, SCAN_BLK, 0, stream>>>(deg, partials, offsets, cursor);
    build_csr_kernel<<<2048, 256, 0, stream>>>(src, dst, cursor, csr);

    const int AGG_BLOCKS = 25000;  // 4 waves/block -> one wave per node

    // ---- layer 1 (fin=13): agg x -> bufA (padded stride 64), MLP in place ----
    agg_kernel<NF><<<AGG_BLOCKS, 256, 0, stream>>>(x, offsets, csr, bufA);
    mlp_kernel<NF><<<4096, 256, 0, stream>>>(
        bufA, c1[0], c1[1], c1[2], c1[3], c1[4], c1[5], c1[6], c1[7],
        pool, batch, 0);

    // ---- layer 2 (fin=64): agg h1(bufA) -> bufB, MLP in place ----
    agg_kernel<64><<<AGG_BLOCKS, 256, 0, stream>>>(bufA, offsets, csr, bufB);
    mlp_kernel<64><<<4096, 256, 0, stream>>>(
        bufB, c2[0], c2[1], c2[2], c2[3], c2[4], c2[5], c2[6], c2[7],
        pool, batch, 64);

    // ---- layer 3 (fin=64): agg h2(bufB) -> bufA, MLP in place ----
    agg_kernel<64><<<AGG_BLOCKS, 256, 0, stream>>>(bufB, offsets, csr, bufA);
    mlp_kernel<64><<<4096, 256, 0, stream>>>(
        bufA, c3[0], c3[1], c3[2], c3[3], c3[4], c3[5], c3[6], c3[7],
        pool, batch, 128);

    final_kernel<<<NG, 192, 0, stream>>>(pool, fc1W, fc1b, fc2W, fc2b, out);
}

// Round 4
// 1251.783 us; speedup vs baseline: 1.8144x; 1.0682x over previous
//
#include <hip/hip_runtime.h>

#define NNODES 100000
#define NEDGES 3200000
#define NF 13
#define NFP 16       // padded bf16 row stride for x
#define NG 512
#define BN_EPS 1e-5f

#define SCAN_BLK 256
#define NBLK ((NNODES + SCAN_BLK - 1) / SCAN_BLK)   // 391

__device__ __forceinline__ float bf2f(unsigned short u) {
    return __uint_as_float(((unsigned)u) << 16);
}
__device__ __forceinline__ unsigned short f2bf(float f) {
    unsigned u = __float_as_uint(f);
    unsigned r = (u + 0x7FFFu + ((u >> 16) & 1u)) >> 16;  // RNE
    return (unsigned short)r;
}

// ---------------- CSR build: histogram of dst ----------------
__global__ void hist_kernel(const int* __restrict__ dst, int* __restrict__ deg) {
    int idx = blockIdx.x * blockDim.x + threadIdx.x;
    int stride = gridDim.x * blockDim.x;
    for (int e = idx; e < NEDGES; e += stride) atomicAdd(&deg[dst[e]], 1);
}

// ---------------- per-block partial sums of deg ----------------
__global__ void partial_sum_kernel(const int* __restrict__ deg, int* __restrict__ partials) {
    __shared__ int s[SCAN_BLK];
    int t = threadIdx.x;
    int i = blockIdx.x * SCAN_BLK + t;
    s[t] = (i < NNODES) ? deg[i] : 0;
    __syncthreads();
    for (int off = SCAN_BLK / 2; off > 0; off >>= 1) {
        if (t < off) s[t] += s[t + off];
        __syncthreads();
    }
    if (t == 0) partials[blockIdx.x] = s[0];
}

// ---------------- exclusive scan of partials (single block, 512 >= NBLK) --------------
__global__ void scan_partials_kernel(int* __restrict__ partials) {
    __shared__ int s[512];
    int t = threadIdx.x;
    int v = (t < NBLK) ? partials[t] : 0;
    s[t] = v;
    __syncthreads();
    for (int off = 1; off < 512; off <<= 1) {
        int tmp = (t >= off) ? s[t - off] : 0;
        __syncthreads();
        s[t] += tmp;
        __syncthreads();
    }
    if (t < NBLK) partials[t] = s[t] - v;  // exclusive
}

// ---------------- per-block exclusive scan -> offsets, cursor ----------------
__global__ void scan_block_kernel(const int* __restrict__ deg, const int* __restrict__ partials,
                                  int* __restrict__ offsets, int* __restrict__ cursor) {
    __shared__ int s[SCAN_BLK];
    int t = threadIdx.x;
    int i = blockIdx.x * SCAN_BLK + t;
    int v = (i < NNODES) ? deg[i] : 0;
    s[t] = v;
    __syncthreads();
    for (int off = 1; off < SCAN_BLK; off <<= 1) {
        int tmp = (t >= off) ? s[t - off] : 0;
        __syncthreads();
        s[t] += tmp;
        __syncthreads();
    }
    if (i < NNODES) {
        int excl = partials[blockIdx.x] + s[t] - v;
        offsets[i] = excl;
        cursor[i] = excl;
    }
    if (i == 0) offsets[NNODES] = NEDGES;
}

// ---------------- scatter edges into CSR slots ----------------
__global__ void build_csr_kernel(const int* __restrict__ src, const int* __restrict__ dst,
                                 int* __restrict__ cursor, int* __restrict__ csr) {
    int idx = blockIdx.x * blockDim.x + threadIdx.x;
    int stride = gridDim.x * blockDim.x;
    for (int e = idx; e < NEDGES; e += stride) {
        int pos = atomicAdd(&cursor[dst[e]], 1);
        csr[pos] = src[e];
    }
}

// ---------------- convert x (fp32, stride 13) -> xbf (bf16, stride 16) ----------------
__global__ void cvt_x_kernel(const float* __restrict__ x, unsigned short* __restrict__ xbf) {
    const int total = NNODES * NF;
    int idx = blockIdx.x * blockDim.x + threadIdx.x;
    int stride = gridDim.x * blockDim.x;
    for (int i = idx; i < total; i += stride) {
        int n = i / NF;
        int f = i - n * NF;
        xbf[n * NFP + f] = f2bf(x[i]);
    }
}

// ---------------- lean bf16 aggregation: y[n] = x[n] + sum_{j in N(n)} x[j] ------------
// One wave per node, lane = feature. Input rows bf16 (2 B/lane gathers), fp32 accumulate.
// Output y fp32, stride 64.
template <int FIN, int FSTR>
__launch_bounds__(256, 8)
__global__ void agg_bf16_kernel(const unsigned short* __restrict__ xin,
                                const int* __restrict__ offsets,
                                const int* __restrict__ csr,
                                float* __restrict__ y) {
    int lane = threadIdx.x & 63;
    int wave = (blockIdx.x * blockDim.x + threadIdx.x) >> 6;
    int nw = (gridDim.x * blockDim.x) >> 6;
    const bool act = (FIN == 64) || (lane < FIN);
    for (int n = wave; n < NNODES; n += nw) {
        int beg = offsets[n], end = offsets[n + 1];
        float acc = act ? bf2f(xin[n * FSTR + lane]) : 0.f;
        int j = beg;
        for (; j + 8 <= end; j += 8) {
            int s0 = csr[j + 0], s1 = csr[j + 1], s2 = csr[j + 2], s3 = csr[j + 3];
            int s4 = csr[j + 4], s5 = csr[j + 5], s6 = csr[j + 6], s7 = csr[j + 7];
            float a0 = 0.f, a1 = 0.f, a2 = 0.f, a3 = 0.f;
            float a4 = 0.f, a5 = 0.f, a6 = 0.f, a7 = 0.f;
            if (act) {
                a0 = bf2f(xin[s0 * FSTR + lane]); a1 = bf2f(xin[s1 * FSTR + lane]);
                a2 = bf2f(xin[s2 * FSTR + lane]); a3 = bf2f(xin[s3 * FSTR + lane]);
                a4 = bf2f(xin[s4 * FSTR + lane]); a5 = bf2f(xin[s5 * FSTR + lane]);
                a6 = bf2f(xin[s6 * FSTR + lane]); a7 = bf2f(xin[s7 * FSTR + lane]);
            }
            acc += ((a0 + a1) + (a2 + a3)) + ((a4 + a5) + (a6 + a7));
        }
        for (; j + 4 <= end; j += 4) {
            int s0 = csr[j + 0], s1 = csr[j + 1], s2 = csr[j + 2], s3 = csr[j + 3];
            float a0 = 0.f, a1 = 0.f, a2 = 0.f, a3 = 0.f;
            if (act) {
                a0 = bf2f(xin[s0 * FSTR + lane]); a1 = bf2f(xin[s1 * FSTR + lane]);
                a2 = bf2f(xin[s2 * FSTR + lane]); a3 = bf2f(xin[s3 * FSTR + lane]);
            }
            acc += (a0 + a1) + (a2 + a3);
        }
        for (; j < end; ++j) {
            int s0 = csr[j];
            if (act) acc += bf2f(xin[s0 * FSTR + lane]);
        }
        if (act) y[n * 64 + lane] = acc;
    }
}

// ---------------- MLP: h = relu(relu(BN(y@W1+b1))@W2+b2); pool fp32; hout bf16 --------
// One wave per node; reads fp32 y row (stride 64), writes bf16 h (stride 64) if hout!=0.
template <int FIN>
__launch_bounds__(256)
__global__ void mlp_kernel(const float* __restrict__ buf,
                           const float* __restrict__ W1, const float* __restrict__ b1,
                           const float* __restrict__ g,  const float* __restrict__ be,
                           const float* __restrict__ m,  const float* __restrict__ v,
                           const float* __restrict__ W2, const float* __restrict__ b2,
                           unsigned short* __restrict__ hout,
                           float* __restrict__ pool, const int* __restrict__ batch,
                           int poolOff) {
    __shared__ float W1s[FIN * 64];
    __shared__ float W2s[64 * 64];
    for (int i = threadIdx.x; i < FIN * 64; i += 256) W1s[i] = W1[i];
    for (int i = threadIdx.x; i < 64 * 64; i += 256) W2s[i] = W2[i];
    __syncthreads();

    int lane = threadIdx.x & 63;
    int wave = (blockIdx.x * blockDim.x + threadIdx.x) >> 6;
    int nw = (gridDim.x * blockDim.x) >> 6;

    float scale = g[lane] * rsqrtf(v[lane] + BN_EPS);
    float shift = be[lane] - m[lane] * scale;
    float bb1 = b1[lane];
    float bb2 = b2[lane];

    for (int n = wave; n < NNODES; n += nw) {
        float y = 0.f;
        if (lane < FIN) y = buf[n * 64 + lane];
        float acc = 0.f;
#pragma unroll
        for (int k = 0; k < FIN; ++k) {
            float yk = __shfl(y, k, 64);
            acc = fmaf(yk, W1s[k * 64 + lane], acc);
        }
        float z = fmaxf(fmaf(acc + bb1, scale, shift), 0.f);
        float acc2 = 0.f;
#pragma unroll
        for (int k = 0; k < 64; ++k) {
            float zk = __shfl(z, k, 64);
            acc2 = fmaf(zk, W2s[k * 64 + lane], acc2);
        }
        float h = fmaxf(acc2 + bb2, 0.f);
        if (hout) hout[n * 64 + lane] = f2bf(h);
        atomicAdd(&pool[batch[n] * 192 + poolOff + lane], h);
    }
}

// ---------------- FC head: relu(p@fc1W+fc1b) @ fc2W + fc2b, log_softmax --------------
__global__ void final_kernel(const float* __restrict__ pool,
                             const float* __restrict__ fc1W, const float* __restrict__ fc1b,
                             const float* __restrict__ fc2W, const float* __restrict__ fc2b,
                             float* __restrict__ out) {
    __shared__ float ps[192];
    __shared__ float hs[192];
    int gi = blockIdx.x;
    int t = threadIdx.x;  // 192
    ps[t] = pool[gi * 192 + t];
    __syncthreads();
    float acc = fc1b[t];
#pragma unroll 8
    for (int k = 0; k < 192; ++k) acc = fmaf(ps[k], fc1W[k * 192 + t], acc);
    hs[t] = fmaxf(acc, 0.f);
    __syncthreads();
    if (t == 0) {
        float l0 = fc2b[0], l1 = fc2b[1];
        for (int k = 0; k < 192; ++k) {
            float h = hs[k];
            l0 = fmaf(h, fc2W[k * 2 + 0], l0);
            l1 = fmaf(h, fc2W[k * 2 + 1], l1);
        }
        float mx = fmaxf(l0, l1);
        float lse = mx + logf(expf(l0 - mx) + expf(l1 - mx));
        out[gi * 2 + 0] = l0 - lse;
        out[gi * 2 + 1] = l1 - lse;
    }
}

extern "C" void kernel_launch(void* const* d_in, const int* in_sizes, int n_in,
                              void* d_out, int out_size, void* d_ws, size_t ws_size,
                              hipStream_t stream) {
    const float* x = (const float*)d_in[0];
    const int* src = (const int*)d_in[1];
    const int* dst = (const int*)d_in[2];
    const int* batch = (const int*)d_in[3];
    const float* c1[8];
    const float* c2[8];
    const float* c3[8];
    for (int i = 0; i < 8; ++i) {
        c1[i] = (const float*)d_in[4 + i];
        c2[i] = (const float*)d_in[12 + i];
        c3[i] = (const float*)d_in[20 + i];
    }
    const float* fc1W = (const float*)d_in[28];
    const float* fc1b = (const float*)d_in[29];
    const float* fc2W = (const float*)d_in[30];
    const float* fc2b = (const float*)d_in[31];
    float* out = (float*)d_out;

    // ---- workspace layout ----
    float* ws = (float*)d_ws;
    const size_t NA = (size_t)NNODES * 64;
    float* ybuf = ws;                          // fp32 agg output, reused each layer (25.6 MB)
    float* pool = ws + NA;                     // G*192
    unsigned short* xbf = (unsigned short*)(pool + (size_t)NG * 192);  // N*16 bf16
    unsigned short* hbf = xbf + (size_t)NNODES * NFP;                  // N*64 bf16, reused
    int* ibase = (int*)(hbf + NA);
    int* deg      = ibase;                    // N
    int* offsets  = ibase + NNODES;           // N+1
    int* cursor   = offsets + NNODES + 1;     // N
    int* csr      = cursor + NNODES;          // E
    int* partials = csr + NEDGES;             // NBLK

    hipMemsetAsync(pool, 0, (size_t)NG * 192 * sizeof(float), stream);
    hipMemsetAsync(deg, 0, (size_t)NNODES * sizeof(int), stream);

    // ---- build CSR by dst (once; reused by all 3 layers) + convert x to bf16 ----
    hist_kernel<<<4096, 256, 0, stream>>>(dst, deg);
    cvt_x_kernel<<<2048, 256, 0, stream>>>(x, xbf);
    partial_sum_kernel<<<NBLK, SCAN_BLK, 0, stream>>>(deg, partials);
    scan_partials_kernel<<<1, 512, 0, stream>>>(partials);
    scan_block_kernel<<<NBLK, SCAN_BLK, 0, stream>>>(deg, partials, offsets, cursor);
    build_csr_kernel<<<2048, 256, 0, stream>>>(src, dst, cursor, csr);

    const int AGG_BLOCKS = 25000;  // 4 waves/block -> one wave per node

    // ---- layer 1 (fin=13): agg xbf -> ybuf, MLP -> hbf (bf16) ----
    agg_bf16_kernel<NF, NFP><<<AGG_BLOCKS, 256, 0, stream>>>(xbf, offsets, csr, ybuf);
    mlp_kernel<NF><<<4096, 256, 0, stream>>>(
        ybuf, c1[0], c1[1], c1[2], c1[3], c1[4], c1[5], c1[6], c1[7],
        hbf, pool, batch, 0);

    // ---- layer 2 (fin=64): agg hbf -> ybuf, MLP -> hbf (overwrite after read) ----
    agg_bf16_kernel<64, 64><<<AGG_BLOCKS, 256, 0, stream>>>(hbf, offsets, csr, ybuf);
    mlp_kernel<64><<<4096, 256, 0, stream>>>(
        ybuf, c2[0], c2[1], c2[2], c2[3], c2[4], c2[5], c2[6], c2[7],
        hbf, pool, batch, 64);

    // ---- layer 3 (fin=64): agg hbf -> ybuf, MLP pools only (no h write) ----
    agg_bf16_kernel<64, 64><<<AGG_BLOCKS, 256, 0, stream>>>(hbf, offsets, csr, ybuf);
    mlp_kernel<64><<<4096, 256, 0, stream>>>(
        ybuf, c3[0], c3[1], c3[2], c3[3], c3[4], c3[5], c3[6], c3[7],
        (unsigned short*)nullptr, pool, batch, 128);

    final_kernel<<<NG, 192, 0, stream>>>(pool, fc1W, fc1b, fc2W, fc2b, out);
}

// Round 5
// 1193.410 us; speedup vs baseline: 1.9031x; 1.0489x over previous
//
#include <hip/hip_runtime.h>

#define NNODES 100000
#define NEDGES 3200000
#define NF 13
#define NFP 16       // padded bf16 row stride for x
#define NG 512
#define BN_EPS 1e-5f

#define SCAN_BLK 256
#define NBLK ((NNODES + SCAN_BLK - 1) / SCAN_BLK)   // 391

__device__ __forceinline__ float bf2f(unsigned short u) {
    return __uint_as_float(((unsigned)u) << 16);
}
__device__ __forceinline__ unsigned short f2bf(float f) {
    unsigned u = __float_as_uint(f);
    unsigned r = (u + 0x7FFFu + ((u >> 16) & 1u)) >> 16;  // RNE
    return (unsigned short)r;
}

// ---------------- CSR build: histogram of dst ----------------
__global__ void hist_kernel(const int* __restrict__ dst, int* __restrict__ deg) {
    int idx = blockIdx.x * blockDim.x + threadIdx.x;
    int stride = gridDim.x * blockDim.x;
    for (int e = idx; e < NEDGES; e += stride) atomicAdd(&deg[dst[e]], 1);
}

// ---------------- per-block partial sums of deg ----------------
__global__ void partial_sum_kernel(const int* __restrict__ deg, int* __restrict__ partials) {
    __shared__ int s[SCAN_BLK];
    int t = threadIdx.x;
    int i = blockIdx.x * SCAN_BLK + t;
    s[t] = (i < NNODES) ? deg[i] : 0;
    __syncthreads();
    for (int off = SCAN_BLK / 2; off > 0; off >>= 1) {
        if (t < off) s[t] += s[t + off];
        __syncthreads();
    }
    if (t == 0) partials[blockIdx.x] = s[0];
}

// ---------------- exclusive scan of partials (single block, 512 >= NBLK) --------------
__global__ void scan_partials_kernel(int* __restrict__ partials) {
    __shared__ int s[512];
    int t = threadIdx.x;
    int v = (t < NBLK) ? partials[t] : 0;
    s[t] = v;
    __syncthreads();
    for (int off = 1; off < 512; off <<= 1) {
        int tmp = (t >= off) ? s[t - off] : 0;
        __syncthreads();
        s[t] += tmp;
        __syncthreads();
    }
    if (t < NBLK) partials[t] = s[t] - v;  // exclusive
}

// ---------------- per-block exclusive scan -> offsets, cursor ----------------
__global__ void scan_block_kernel(const int* __restrict__ deg, const int* __restrict__ partials,
                                  int* __restrict__ offsets, int* __restrict__ cursor) {
    __shared__ int s[SCAN_BLK];
    int t = threadIdx.x;
    int i = blockIdx.x * SCAN_BLK + t;
    int v = (i < NNODES) ? deg[i] : 0;
    s[t] = v;
    __syncthreads();
    for (int off = 1; off < SCAN_BLK; off <<= 1) {
        int tmp = (t >= off) ? s[t - off] : 0;
        __syncthreads();
        s[t] += tmp;
        __syncthreads();
    }
    if (i < NNODES) {
        int excl = partials[blockIdx.x] + s[t] - v;
        offsets[i] = excl;
        cursor[i] = excl;
    }
    if (i == 0) offsets[NNODES] = NEDGES;
}

// ---------------- scatter edges into CSR slots ----------------
__global__ void build_csr_kernel(const int* __restrict__ src, const int* __restrict__ dst,
                                 int* __restrict__ cursor, int* __restrict__ csr) {
    int idx = blockIdx.x * blockDim.x + threadIdx.x;
    int stride = gridDim.x * blockDim.x;
    for (int e = idx; e < NEDGES; e += stride) {
        int pos = atomicAdd(&cursor[dst[e]], 1);
        csr[pos] = src[e];
    }
}

// ---------------- convert x (fp32, stride 13) -> xbf (bf16, stride 16, zero-padded) ---
__global__ void cvt_x_kernel(const float* __restrict__ x, unsigned short* __restrict__ xbf) {
    const int total = NNODES * NFP;
    int idx = blockIdx.x * blockDim.x + threadIdx.x;
    int stride = gridDim.x * blockDim.x;
    for (int i = idx; i < total; i += stride) {
        int n = i >> 4;
        int f = i & 15;
        xbf[i] = (f < NF) ? f2bf(x[n * NF + f]) : (unsigned short)0;
    }
}

// ---------------- vectorized bf16 aggregation ----------------
// One wave per node. A row is FSTR bf16 = FSTR*2 bytes; RL lanes x ushort4 (8 B) cover
// one row, so one wave-wide gather fetches EPG = 64/RL edge rows at once.
// Lane g = lane/RL selects edge slot, r = lane%RL selects the row chunk (features r*4..+3).
// Partial sums reduced across groups with shfl_xor at the end. Output y fp32, stride 64.
template <int FSTR, int RL, int UNROLL>
__launch_bounds__(256, 8)
__global__ void agg_vec_kernel(const unsigned short* __restrict__ xin,
                               const int* __restrict__ offsets,
                               const int* __restrict__ csr,
                               float* __restrict__ y) {
    const int EPG = 64 / RL;
    int lane = threadIdx.x & 63;
    int g = lane / RL;
    int r = lane % RL;
    int wave = (blockIdx.x * blockDim.x + threadIdx.x) >> 6;
    int nw = (gridDim.x * blockDim.x) >> 6;

    for (int n = wave; n < NNODES; n += nw) {
        int beg = offsets[n], end = offsets[n + 1];
        float ax = 0.f, ay = 0.f, az = 0.f, aw = 0.f;
        if (g == 0) {  // self row, added once
            ushort4 u = *(const ushort4*)&xin[n * FSTR + r * 4];
            ax = bf2f(u.x); ay = bf2f(u.y); az = bf2f(u.z); aw = bf2f(u.w);
        }
        int j = beg;
        const int STEP = UNROLL * EPG;
        for (; j + STEP <= end; j += STEP) {
#pragma unroll
            for (int t = 0; t < UNROLL; ++t) {
                int e = j + t * EPG + g;           // guaranteed < end
                int i0 = csr[e];
                ushort4 u = *(const ushort4*)&xin[i0 * FSTR + r * 4];
                ax += bf2f(u.x); ay += bf2f(u.y); az += bf2f(u.z); aw += bf2f(u.w);
            }
        }
        for (; j < end; j += EPG) {
            int e = j + g;
            if (e < end) {
                int i0 = csr[e];
                ushort4 u = *(const ushort4*)&xin[i0 * FSTR + r * 4];
                ax += bf2f(u.x); ay += bf2f(u.y); az += bf2f(u.z); aw += bf2f(u.w);
            }
        }
        // reduce partial sums across the EPG lane groups
#pragma unroll
        for (int m = RL; m < 64; m <<= 1) {
            ax += __shfl_xor(ax, m, 64);
            ay += __shfl_xor(ay, m, 64);
            az += __shfl_xor(az, m, 64);
            aw += __shfl_xor(aw, m, 64);
        }
        if (g == 0) {
            float4 o = make_float4(ax, ay, az, aw);
            *(float4*)&y[n * 64 + r * 4] = o;
        }
    }
}

// ---------------- MLP: h = relu(relu(BN(y@W1+b1))@W2+b2); pool fp32; hout bf16 --------
template <int FIN>
__launch_bounds__(256)
__global__ void mlp_kernel(const float* __restrict__ buf,
                           const float* __restrict__ W1, const float* __restrict__ b1,
                           const float* __restrict__ g,  const float* __restrict__ be,
                           const float* __restrict__ m,  const float* __restrict__ v,
                           const float* __restrict__ W2, const float* __restrict__ b2,
                           unsigned short* __restrict__ hout,
                           float* __restrict__ pool, const int* __restrict__ batch,
                           int poolOff) {
    __shared__ float W1s[FIN * 64];
    __shared__ float W2s[64 * 64];
    for (int i = threadIdx.x; i < FIN * 64; i += 256) W1s[i] = W1[i];
    for (int i = threadIdx.x; i < 64 * 64; i += 256) W2s[i] = W2[i];
    __syncthreads();

    int lane = threadIdx.x & 63;
    int wave = (blockIdx.x * blockDim.x + threadIdx.x) >> 6;
    int nw = (gridDim.x * blockDim.x) >> 6;

    float scale = g[lane] * rsqrtf(v[lane] + BN_EPS);
    float shift = be[lane] - m[lane] * scale;
    float bb1 = b1[lane];
    float bb2 = b2[lane];

    for (int n = wave; n < NNODES; n += nw) {
        float y = 0.f;
        if (lane < FIN) y = buf[n * 64 + lane];
        float acc = 0.f;
#pragma unroll
        for (int k = 0; k < FIN; ++k) {
            float yk = __shfl(y, k, 64);
            acc = fmaf(yk, W1s[k * 64 + lane], acc);
        }
        float z = fmaxf(fmaf(acc + bb1, scale, shift), 0.f);
        float acc2 = 0.f;
#pragma unroll
        for (int k = 0; k < 64; ++k) {
            float zk = __shfl(z, k, 64);
            acc2 = fmaf(zk, W2s[k * 64 + lane], acc2);
        }
        float h = fmaxf(acc2 + bb2, 0.f);
        if (hout) hout[n * 64 + lane] = f2bf(h);
        atomicAdd(&pool[batch[n] * 192 + poolOff + lane], h);
    }
}

// ---------------- FC head: relu(p@fc1W+fc1b) @ fc2W + fc2b, log_softmax --------------
__global__ void final_kernel(const float* __restrict__ pool,
                             const float* __restrict__ fc1W, const float* __restrict__ fc1b,
                             const float* __restrict__ fc2W, const float* __restrict__ fc2b,
                             float* __restrict__ out) {
    __shared__ float ps[192];
    __shared__ float hs[192];
    int gi = blockIdx.x;
    int t = threadIdx.x;  // 192
    ps[t] = pool[gi * 192 + t];
    __syncthreads();
    float acc = fc1b[t];
#pragma unroll 8
    for (int k = 0; k < 192; ++k) acc = fmaf(ps[k], fc1W[k * 192 + t], acc);
    hs[t] = fmaxf(acc, 0.f);
    __syncthreads();
    if (t == 0) {
        float l0 = fc2b[0], l1 = fc2b[1];
        for (int k = 0; k < 192; ++k) {
            float h = hs[k];
            l0 = fmaf(h, fc2W[k * 2 + 0], l0);
            l1 = fmaf(h, fc2W[k * 2 + 1], l1);
        }
        float mx = fmaxf(l0, l1);
        float lse = mx + logf(expf(l0 - mx) + expf(l1 - mx));
        out[gi * 2 + 0] = l0 - lse;
        out[gi * 2 + 1] = l1 - lse;
    }
}

extern "C" void kernel_launch(void* const* d_in, const int* in_sizes, int n_in,
                              void* d_out, int out_size, void* d_ws, size_t ws_size,
                              hipStream_t stream) {
    const float* x = (const float*)d_in[0];
    const int* src = (const int*)d_in[1];
    const int* dst = (const int*)d_in[2];
    const int* batch = (const int*)d_in[3];
    const float* c1[8];
    const float* c2[8];
    const float* c3[8];
    for (int i = 0; i < 8; ++i) {
        c1[i] = (const float*)d_in[4 + i];
        c2[i] = (const float*)d_in[12 + i];
        c3[i] = (const float*)d_in[20 + i];
    }
    const float* fc1W = (const float*)d_in[28];
    const float* fc1b = (const float*)d_in[29];
    const float* fc2W = (const float*)d_in[30];
    const float* fc2b = (const float*)d_in[31];
    float* out = (float*)d_out;

    // ---- workspace layout ----
    float* ws = (float*)d_ws;
    const size_t NA = (size_t)NNODES * 64;
    float* ybuf = ws;                          // fp32 agg output, reused each layer (25.6 MB)
    float* pool = ws + NA;                     // G*192
    unsigned short* xbf = (unsigned short*)(pool + (size_t)NG * 192);  // N*16 bf16 (8B-aligned)
    unsigned short* hbf = xbf + (size_t)NNODES * NFP;                  // N*64 bf16, reused
    int* ibase = (int*)(hbf + NA);
    int* deg      = ibase;                    // N
    int* offsets  = ibase + NNODES;           // N+1
    int* cursor   = offsets + NNODES + 1;     // N
    int* csr      = cursor + NNODES;          // E
    int* partials = csr + NEDGES;             // NBLK

    hipMemsetAsync(pool, 0, (size_t)NG * 192 * sizeof(float), stream);
    hipMemsetAsync(deg, 0, (size_t)NNODES * sizeof(int), stream);

    // ---- build CSR by dst (once; reused by all 3 layers) + convert x to bf16 ----
    hist_kernel<<<4096, 256, 0, stream>>>(dst, deg);
    cvt_x_kernel<<<2048, 256, 0, stream>>>(x, xbf);
    partial_sum_kernel<<<NBLK, SCAN_BLK, 0, stream>>>(deg, partials);
    scan_partials_kernel<<<1, 512, 0, stream>>>(partials);
    scan_block_kernel<<<NBLK, SCAN_BLK, 0, stream>>>(deg, partials, offsets, cursor);
    build_csr_kernel<<<2048, 256, 0, stream>>>(src, dst, cursor, csr);

    const int AGG_BLOCKS = 25000;  // 4 waves/block -> one wave per node

    // ---- layer 1 (fin=13, 32 B rows): 16 edges/gather ----
    agg_vec_kernel<NFP, 4, 2><<<AGG_BLOCKS, 256, 0, stream>>>(xbf, offsets, csr, ybuf);
    mlp_kernel<NF><<<4096, 256, 0, stream>>>(
        ybuf, c1[0], c1[1], c1[2], c1[3], c1[4], c1[5], c1[6], c1[7],
        hbf, pool, batch, 0);

    // ---- layer 2 (fin=64, 128 B rows): 4 edges/gather ----
    agg_vec_kernel<64, 16, 4><<<AGG_BLOCKS, 256, 0, stream>>>(hbf, offsets, csr, ybuf);
    mlp_kernel<64><<<4096, 256, 0, stream>>>(
        ybuf, c2[0], c2[1], c2[2], c2[3], c2[4], c2[5], c2[6], c2[7],
        hbf, pool, batch, 64);

    // ---- layer 3 (fin=64): agg, MLP pools only (no h write) ----
    agg_vec_kernel<64, 16, 4><<<AGG_BLOCKS, 256, 0, stream>>>(hbf, offsets, csr, ybuf);
    mlp_kernel<64><<<4096, 256, 0, stream>>>(
        ybuf, c3[0], c3[1], c3[2], c3[3], c3[4], c3[5], c3[6], c3[7],
        (unsigned short*)nullptr, pool, batch, 128);

    final_kernel<<<NG, 192, 0, stream>>>(pool, fc1W, fc1b, fc2W, fc2b, out);
}

// Round 6
// 1036.196 us; speedup vs baseline: 2.1918x; 1.1517x over previous
//
#include <hip/hip_runtime.h>

#define NNODES 100000
#define NEDGES 3200000
#define NF 13
#define NFP 16       // padded bf16 row stride for x
#define NG 512
#define BN_EPS 1e-5f

#define SCAN_BLK 256
#define NBLK ((NNODES + SCAN_BLK - 1) / SCAN_BLK)   // 391

#define NPASS 16
#define BUCKET (NNODES / NPASS)   // 6250 exactly
#define CPB 128                   // blocks per pass; grid = NPASS*CPB = 2048

__device__ __forceinline__ float bf2f(unsigned short u) {
    return __uint_as_float(((unsigned)u) << 16);
}
__device__ __forceinline__ unsigned short f2bf(float f) {
    unsigned u = __float_as_uint(f);
    unsigned r = (u + 0x7FFFu + ((u >> 16) & 1u)) >> 16;  // RNE
    return (unsigned short)r;
}

// ---------------- CSR build: histogram of dst ----------------
__global__ void hist_kernel(const int* __restrict__ dst, int* __restrict__ deg) {
    int idx = blockIdx.x * blockDim.x + threadIdx.x;
    int stride = gridDim.x * blockDim.x;
    for (int e = idx; e < NEDGES; e += stride) atomicAdd(&deg[dst[e]], 1);
}

// ---------------- per-block partial sums of deg ----------------
__global__ void partial_sum_kernel(const int* __restrict__ deg, int* __restrict__ partials) {
    __shared__ int s[SCAN_BLK];
    int t = threadIdx.x;
    int i = blockIdx.x * SCAN_BLK + t;
    s[t] = (i < NNODES) ? deg[i] : 0;
    __syncthreads();
    for (int off = SCAN_BLK / 2; off > 0; off >>= 1) {
        if (t < off) s[t] += s[t + off];
        __syncthreads();
    }
    if (t == 0) partials[blockIdx.x] = s[0];
}

// ---------------- exclusive scan of partials (single block, 512 >= NBLK) --------------
__global__ void scan_partials_kernel(int* __restrict__ partials) {
    __shared__ int s[512];
    int t = threadIdx.x;
    int v = (t < NBLK) ? partials[t] : 0;
    s[t] = v;
    __syncthreads();
    for (int off = 1; off < 512; off <<= 1) {
        int tmp = (t >= off) ? s[t - off] : 0;
        __syncthreads();
        s[t] += tmp;
        __syncthreads();
    }
    if (t < NBLK) partials[t] = s[t] - v;  // exclusive
}

// ---------------- per-block exclusive scan -> offsets, cursor ----------------
__global__ void scan_block_kernel(const int* __restrict__ deg, const int* __restrict__ partials,
                                  int* __restrict__ offsets, int* __restrict__ cursor) {
    __shared__ int s[SCAN_BLK];
    int t = threadIdx.x;
    int i = blockIdx.x * SCAN_BLK + t;
    int v = (i < NNODES) ? deg[i] : 0;
    s[t] = v;
    __syncthreads();
    for (int off = 1; off < SCAN_BLK; off <<= 1) {
        int tmp = (t >= off) ? s[t - off] : 0;
        __syncthreads();
        s[t] += tmp;
        __syncthreads();
    }
    if (i < NNODES) {
        int excl = partials[blockIdx.x] + s[t] - v;
        offsets[i] = excl;
        cursor[i] = excl;
    }
    if (i == 0) offsets[NNODES] = NEDGES;
}

// ---------------- bucketed CSR scatter: 16 dst-range passes in one launch -------------
// pass = blockIdx&15 so that all blocks of a pass share blockIdx%8 (one XCD per the
// heuristic XCD swizzle) -> each ~0.8 MB csr slice stays in ONE L2 and lines fill
// before writeback (kills the 16x write amplification). Correct regardless of mapping.
__global__ void build_csr_pass_kernel(const int* __restrict__ src, const int* __restrict__ dst,
                                      int* __restrict__ cursor, int* __restrict__ csr) {
    int pass = blockIdx.x & (NPASS - 1);
    int chunk = blockIdx.x >> 4;              // [0, CPB)
    int lo = pass * BUCKET, hi = lo + BUCKET;
    int e = chunk * blockDim.x + threadIdx.x;
    const int stride = CPB * 256;
    for (; e < NEDGES; e += stride) {
        int d = dst[e];
        if (d >= lo && d < hi) {
            int p = atomicAdd(&cursor[d], 1);
            csr[p] = src[e];
        }
    }
}

// ---------------- convert x (fp32, stride 13) -> xbf (bf16, stride 16, zero-padded) ---
__global__ void cvt_x_kernel(const float* __restrict__ x, unsigned short* __restrict__ xbf) {
    const int total = NNODES * NFP;
    int idx = blockIdx.x * blockDim.x + threadIdx.x;
    int stride = gridDim.x * blockDim.x;
    for (int i = idx; i < total; i += stride) {
        int n = i >> 4;
        int f = i & 15;
        xbf[i] = (f < NF) ? f2bf(x[n * NF + f]) : (unsigned short)0;
    }
}

// ---------------- vectorized bf16 aggregation ----------------
// One wave per node. RL lanes x ushort4 cover one row; one gather fetches 64/RL rows.
// Output y bf16, stride 64.
template <int FSTR, int RL, int UNROLL>
__launch_bounds__(256, 8)
__global__ void agg_vec_kernel(const unsigned short* __restrict__ xin,
                               const int* __restrict__ offsets,
                               const int* __restrict__ csr,
                               unsigned short* __restrict__ y) {
    const int EPG = 64 / RL;
    int lane = threadIdx.x & 63;
    int g = lane / RL;
    int r = lane % RL;
    int wave = (blockIdx.x * blockDim.x + threadIdx.x) >> 6;
    int nw = (gridDim.x * blockDim.x) >> 6;

    for (int n = wave; n < NNODES; n += nw) {
        int beg = offsets[n], end = offsets[n + 1];
        float ax = 0.f, ay = 0.f, az = 0.f, aw = 0.f;
        if (g == 0) {  // self row, added once
            ushort4 u = *(const ushort4*)&xin[n * FSTR + r * 4];
            ax = bf2f(u.x); ay = bf2f(u.y); az = bf2f(u.z); aw = bf2f(u.w);
        }
        int j = beg;
        const int STEP = UNROLL * EPG;
        for (; j + STEP <= end; j += STEP) {
#pragma unroll
            for (int t = 0; t < UNROLL; ++t) {
                int e = j + t * EPG + g;           // guaranteed < end
                int i0 = csr[e];
                ushort4 u = *(const ushort4*)&xin[i0 * FSTR + r * 4];
                ax += bf2f(u.x); ay += bf2f(u.y); az += bf2f(u.z); aw += bf2f(u.w);
            }
        }
        for (; j < end; j += EPG) {
            int e = j + g;
            if (e < end) {
                int i0 = csr[e];
                ushort4 u = *(const ushort4*)&xin[i0 * FSTR + r * 4];
                ax += bf2f(u.x); ay += bf2f(u.y); az += bf2f(u.z); aw += bf2f(u.w);
            }
        }
        // reduce partial sums across the EPG lane groups
#pragma unroll
        for (int m = RL; m < 64; m <<= 1) {
            ax += __shfl_xor(ax, m, 64);
            ay += __shfl_xor(ay, m, 64);
            az += __shfl_xor(az, m, 64);
            aw += __shfl_xor(aw, m, 64);
        }
        if (g == 0) {
            ushort4 o;
            o.x = f2bf(ax); o.y = f2bf(ay); o.z = f2bf(az); o.w = f2bf(aw);
            *(ushort4*)&y[n * 64 + r * 4] = o;
        }
    }
}

// ---------------- MLP: h = relu(relu(BN(y@W1+b1))@W2+b2); y bf16 in, h bf16 out ------
template <int FIN>
__launch_bounds__(256)
__global__ void mlp_kernel(const unsigned short* __restrict__ ybf,
                           const float* __restrict__ W1, const float* __restrict__ b1,
                           const float* __restrict__ g,  const float* __restrict__ be,
                           const float* __restrict__ m,  const float* __restrict__ v,
                           const float* __restrict__ W2, const float* __restrict__ b2,
                           unsigned short* __restrict__ hout) {
    __shared__ float W1s[FIN * 64];
    __shared__ float W2s[64 * 64];
    for (int i = threadIdx.x; i < FIN * 64; i += 256) W1s[i] = W1[i];
    for (int i = threadIdx.x; i < 64 * 64; i += 256) W2s[i] = W2[i];
    __syncthreads();

    int lane = threadIdx.x & 63;
    int wave = (blockIdx.x * blockDim.x + threadIdx.x) >> 6;
    int nw = (gridDim.x * blockDim.x) >> 6;

    float scale = g[lane] * rsqrtf(v[lane] + BN_EPS);
    float shift = be[lane] - m[lane] * scale;
    float bb1 = b1[lane];
    float bb2 = b2[lane];

    for (int n = wave; n < NNODES; n += nw) {
        float y = 0.f;
        if (lane < FIN) y = bf2f(ybf[n * 64 + lane]);
        float acc = 0.f;
#pragma unroll
        for (int k = 0; k < FIN; ++k) {
            float yk = __shfl(y, k, 64);
            acc = fmaf(yk, W1s[k * 64 + lane], acc);
        }
        float z = fmaxf(fmaf(acc + bb1, scale, shift), 0.f);
        float acc2 = 0.f;
#pragma unroll
        for (int k = 0; k < 64; ++k) {
            float zk = __shfl(z, k, 64);
            acc2 = fmaf(zk, W2s[k * 64 + lane], acc2);
        }
        float h = fmaxf(acc2 + bb2, 0.f);
        hout[n * 64 + lane] = f2bf(h);
    }
}

// ---------------- pooling + FC head (block per graph; batch sorted -> range scan) -----
__global__ void pool_head_kernel(const unsigned short* __restrict__ h1,
                                 const unsigned short* __restrict__ h2,
                                 const unsigned short* __restrict__ h3,
                                 const int* __restrict__ batch,
                                 const float* __restrict__ fc1W, const float* __restrict__ fc1b,
                                 const float* __restrict__ fc2W, const float* __restrict__ fc2b,
                                 float* __restrict__ out) {
    __shared__ float ps[192];
    __shared__ float hs[192];
    __shared__ int bounds[2];
    int gi = blockIdx.x;
    int t = threadIdx.x;  // 192
    if (t < 2) {
        int target = gi + t;
        int lo = 0, hi = NNODES;
        while (lo < hi) {
            int mid = (lo + hi) >> 1;
            if (batch[mid] < target) lo = mid + 1; else hi = mid;
        }
        bounds[t] = lo;
    }
    __syncthreads();
    int nlo = bounds[0], nhi = bounds[1];
    const unsigned short* hb = (t < 64) ? h1 : (t < 128) ? h2 : h3;
    int f = t & 63;
    float s = 0.f;
    for (int n = nlo; n < nhi; ++n) s += bf2f(hb[n * 64 + f]);
    ps[t] = s;
    __syncthreads();
    float acc = fc1b[t];
#pragma unroll 8
    for (int k = 0; k < 192; ++k) acc = fmaf(ps[k], fc1W[k * 192 + t], acc);
    hs[t] = fmaxf(acc, 0.f);
    __syncthreads();
    if (t == 0) {
        float l0 = fc2b[0], l1 = fc2b[1];
        for (int k = 0; k < 192; ++k) {
            float h = hs[k];
            l0 = fmaf(h, fc2W[k * 2 + 0], l0);
            l1 = fmaf(h, fc2W[k * 2 + 1], l1);
        }
        float mx = fmaxf(l0, l1);
        float lse = mx + logf(expf(l0 - mx) + expf(l1 - mx));
        out[gi * 2 + 0] = l0 - lse;
        out[gi * 2 + 1] = l1 - lse;
    }
}

extern "C" void kernel_launch(void* const* d_in, const int* in_sizes, int n_in,
                              void* d_out, int out_size, void* d_ws, size_t ws_size,
                              hipStream_t stream) {
    const float* x = (const float*)d_in[0];
    const int* src = (const int*)d_in[1];
    const int* dst = (const int*)d_in[2];
    const int* batch = (const int*)d_in[3];
    const float* c1[8];
    const float* c2[8];
    const float* c3[8];
    for (int i = 0; i < 8; ++i) {
        c1[i] = (const float*)d_in[4 + i];
        c2[i] = (const float*)d_in[12 + i];
        c3[i] = (const float*)d_in[20 + i];
    }
    const float* fc1W = (const float*)d_in[28];
    const float* fc1b = (const float*)d_in[29];
    const float* fc2W = (const float*)d_in[30];
    const float* fc2b = (const float*)d_in[31];
    float* out = (float*)d_out;

    // ---- workspace layout (all bf16 activations) ----
    unsigned short* base = (unsigned short*)d_ws;
    const size_t NA = (size_t)NNODES * 64;
    unsigned short* ybf = base;                          // N*64
    unsigned short* xbf = ybf + NA;                      // N*16
    unsigned short* h1  = xbf + (size_t)NNODES * NFP;    // N*64
    unsigned short* h2  = h1 + NA;                       // N*64
    unsigned short* h3  = h2 + NA;                       // N*64
    int* ibase = (int*)(h3 + NA);
    int* deg      = ibase;                    // N
    int* offsets  = ibase + NNODES;           // N+1
    int* cursor   = offsets + NNODES + 1;     // N
    int* csr      = cursor + NNODES;          // E
    int* partials = csr + NEDGES;             // NBLK

    hipMemsetAsync(deg, 0, (size_t)NNODES * sizeof(int), stream);

    // ---- build CSR by dst (once; reused by all 3 layers) + convert x to bf16 ----
    hist_kernel<<<4096, 256, 0, stream>>>(dst, deg);
    cvt_x_kernel<<<2048, 256, 0, stream>>>(x, xbf);
    partial_sum_kernel<<<NBLK, SCAN_BLK, 0, stream>>>(deg, partials);
    scan_partials_kernel<<<1, 512, 0, stream>>>(partials);
    scan_block_kernel<<<NBLK, SCAN_BLK, 0, stream>>>(deg, partials, offsets, cursor);
    build_csr_pass_kernel<<<NPASS * CPB, 256, 0, stream>>>(src, dst, cursor, csr);

    const int AGG_BLOCKS = 25000;  // 4 waves/block -> one wave per node

    // ---- layer 1 (fin=13, 32 B rows): 16 edges/gather ----
    agg_vec_kernel<NFP, 4, 2><<<AGG_BLOCKS, 256, 0, stream>>>(xbf, offsets, csr, ybf);
    mlp_kernel<NF><<<4096, 256, 0, stream>>>(
        ybf, c1[0], c1[1], c1[2], c1[3], c1[4], c1[5], c1[6], c1[7], h1);

    // ---- layer 2 (fin=64, 128 B rows): 4 edges/gather ----
    agg_vec_kernel<64, 16, 4><<<AGG_BLOCKS, 256, 0, stream>>>(h1, offsets, csr, ybf);
    mlp_kernel<64><<<4096, 256, 0, stream>>>(
        ybf, c2[0], c2[1], c2[2], c2[3], c2[4], c2[5], c2[6], c2[7], h2);

    // ---- layer 3 (fin=64) ----
    agg_vec_kernel<64, 16, 4><<<AGG_BLOCKS, 256, 0, stream>>>(h2, offsets, csr, ybf);
    mlp_kernel<64><<<4096, 256, 0, stream>>>(
        ybf, c3[0], c3[1], c3[2], c3[3], c3[4], c3[5], c3[6], c3[7], h3);

    // ---- pooling + FC head fused ----
    pool_head_kernel<<<NG, 192, 0, stream>>>(h1, h2, h3, batch, fc1W, fc1b, fc2W, fc2b, out);
}

// Round 7
// 683.116 us; speedup vs baseline: 3.3247x; 1.5169x over previous
//
#include <hip/hip_runtime.h>

#define NNODES 100000
#define NEDGES 3200000
#define NF 13
#define NFP 16       // padded bf16 row stride for x
#define NG 512
#define BN_EPS 1e-5f
#define NTILES (NNODES / 16)   // 6250 exactly

#define SCAN_BLK 256
#define NBLK ((NNODES + SCAN_BLK - 1) / SCAN_BLK)   // 391

#define NPASS 16
#define BUCKET (NNODES / NPASS)   // 6250 exactly
#define CPB 128                   // blocks per pass; grid = NPASS*CPB = 2048

typedef __attribute__((ext_vector_type(8))) short bf16x8;
typedef __attribute__((ext_vector_type(4))) float f32x4;

__device__ __forceinline__ float bf2f(unsigned short u) {
    return __uint_as_float(((unsigned)u) << 16);
}
__device__ __forceinline__ unsigned short f2bf(float f) {
    unsigned u = __float_as_uint(f);
    unsigned r = (u + 0x7FFFu + ((u >> 16) & 1u)) >> 16;  // RNE
    return (unsigned short)r;
}

// ---------------- CSR build: histogram of dst ----------------
__global__ void hist_kernel(const int* __restrict__ dst, int* __restrict__ deg) {
    int idx = blockIdx.x * blockDim.x + threadIdx.x;
    int stride = gridDim.x * blockDim.x;
    for (int e = idx; e < NEDGES; e += stride) atomicAdd(&deg[dst[e]], 1);
}

// ---------------- per-block partial sums of deg ----------------
__global__ void partial_sum_kernel(const int* __restrict__ deg, int* __restrict__ partials) {
    __shared__ int s[SCAN_BLK];
    int t = threadIdx.x;
    int i = blockIdx.x * SCAN_BLK + t;
    s[t] = (i < NNODES) ? deg[i] : 0;
    __syncthreads();
    for (int off = SCAN_BLK / 2; off > 0; off >>= 1) {
        if (t < off) s[t] += s[t + off];
        __syncthreads();
    }
    if (t == 0) partials[blockIdx.x] = s[0];
}

// ---------------- exclusive scan of partials (single block, 512 >= NBLK) --------------
__global__ void scan_partials_kernel(int* __restrict__ partials) {
    __shared__ int s[512];
    int t = threadIdx.x;
    int v = (t < NBLK) ? partials[t] : 0;
    s[t] = v;
    __syncthreads();
    for (int off = 1; off < 512; off <<= 1) {
        int tmp = (t >= off) ? s[t - off] : 0;
        __syncthreads();
        s[t] += tmp;
        __syncthreads();
    }
    if (t < NBLK) partials[t] = s[t] - v;  // exclusive
}

// ---------------- per-block exclusive scan -> offsets, cursor ----------------
__global__ void scan_block_kernel(const int* __restrict__ deg, const int* __restrict__ partials,
                                  int* __restrict__ offsets, int* __restrict__ cursor) {
    __shared__ int s[SCAN_BLK];
    int t = threadIdx.x;
    int i = blockIdx.x * SCAN_BLK + t;
    int v = (i < NNODES) ? deg[i] : 0;
    s[t] = v;
    __syncthreads();
    for (int off = 1; off < SCAN_BLK; off <<= 1) {
        int tmp = (t >= off) ? s[t - off] : 0;
        __syncthreads();
        s[t] += tmp;
        __syncthreads();
    }
    if (i < NNODES) {
        int excl = partials[blockIdx.x] + s[t] - v;
        offsets[i] = excl;
        cursor[i] = excl;
    }
    if (i == 0) offsets[NNODES] = NEDGES;
}

// ---------------- bucketed CSR scatter; non-temporal edge reads so the stream ---------
// doesn't evict partially-filled csr write lines from L2.
__global__ void build_csr_pass_kernel(const int* __restrict__ src, const int* __restrict__ dst,
                                      int* __restrict__ cursor, int* __restrict__ csr) {
    int pass = blockIdx.x & (NPASS - 1);
    int chunk = blockIdx.x >> 4;              // [0, CPB)
    int lo = pass * BUCKET, hi = lo + BUCKET;
    int e = chunk * blockDim.x + threadIdx.x;
    const int stride = CPB * 256;
    for (; e < NEDGES; e += stride) {
        int d = __builtin_nontemporal_load(dst + e);
        if (d >= lo && d < hi) {
            int s = __builtin_nontemporal_load(src + e);
            int p = atomicAdd(&cursor[d], 1);
            csr[p] = s;
        }
    }
}

// ---------------- convert x (fp32, stride 13) -> xbf (bf16, stride 16, zero-padded) ---
__global__ void cvt_x_kernel(const float* __restrict__ x, unsigned short* __restrict__ xbf) {
    const int total = NNODES * NFP;
    int idx = blockIdx.x * blockDim.x + threadIdx.x;
    int stride = gridDim.x * blockDim.x;
    for (int i = idx; i < total; i += stride) {
        int n = i >> 4;
        int f = i & 15;
        xbf[i] = (f < NF) ? f2bf(x[n * NF + f]) : (unsigned short)0;
    }
}

// ---------------- build MFMA B-fragments for all layer weights (bf16) ----------------
// Per layer: [mat(2)][tile(4)][chunk(2)][lane(64)][8] bf16. B[k][n]: lane holds
// n = lane&15, k = chunk*32 + (lane>>4)*8 + j. Zero outside k < K.
__global__ void build_frags_kernel(const float* __restrict__ w10, const float* __restrict__ w20,
                                   const float* __restrict__ w11, const float* __restrict__ w21,
                                   const float* __restrict__ w12, const float* __restrict__ w22,
                                   unsigned short* __restrict__ wfrag) {
    int tid = blockIdx.x * blockDim.x + threadIdx.x;  // 3072 total
    if (tid >= 3072) return;
    int layer = tid >> 10;
    int rem = tid & 1023;
    int mat = rem >> 9;
    int tile = (rem >> 7) & 3;
    int chunk = (rem >> 6) & 1;
    int lane = rem & 63;
    int quad = lane >> 4, n = lane & 15;
    const float* W = (layer == 0) ? (mat ? w20 : w10)
                   : (layer == 1) ? (mat ? w21 : w11)
                                  : (mat ? w22 : w12);
    int K = (layer == 0 && mat == 0) ? NF : 64;
    unsigned short* o = wfrag + ((size_t)tid) * 8;
#pragma unroll
    for (int j = 0; j < 8; ++j) {
        int k = chunk * 32 + quad * 8 + j;
        float val = (k < K) ? W[k * 64 + tile * 16 + n] : 0.f;
        o[j] = f2bf(val);
    }
}

// ---------------- vectorized bf16 aggregation ----------------
// One wave per node. RL lanes x ushort4 cover one row; one gather fetches 64/RL rows.
// Output y bf16, stride 64. PADZ: zero-fill cols [16,32) (layer-1 MFMA reads k<32).
template <int FSTR, int RL, int UNROLL, int PADZ>
__launch_bounds__(256, 8)
__global__ void agg_vec_kernel(const unsigned short* __restrict__ xin,
                               const int* __restrict__ offsets,
                               const int* __restrict__ csr,
                               unsigned short* __restrict__ y) {
    const int EPG = 64 / RL;
    int lane = threadIdx.x & 63;
    int g = lane / RL;
    int r = lane % RL;
    int wave = (blockIdx.x * blockDim.x + threadIdx.x) >> 6;
    int nw = (gridDim.x * blockDim.x) >> 6;

    for (int n = wave; n < NNODES; n += nw) {
        int beg = offsets[n], end = offsets[n + 1];
        float ax = 0.f, ay = 0.f, az = 0.f, aw = 0.f;
        if (g == 0) {  // self row, added once
            ushort4 u = *(const ushort4*)&xin[n * FSTR + r * 4];
            ax = bf2f(u.x); ay = bf2f(u.y); az = bf2f(u.z); aw = bf2f(u.w);
        }
        int j = beg;
        const int STEP = UNROLL * EPG;
        for (; j + STEP <= end; j += STEP) {
#pragma unroll
            for (int t = 0; t < UNROLL; ++t) {
                int e = j + t * EPG + g;           // guaranteed < end
                int i0 = csr[e];
                ushort4 u = *(const ushort4*)&xin[i0 * FSTR + r * 4];
                ax += bf2f(u.x); ay += bf2f(u.y); az += bf2f(u.z); aw += bf2f(u.w);
            }
        }
        for (; j < end; j += EPG) {
            int e = j + g;
            if (e < end) {
                int i0 = csr[e];
                ushort4 u = *(const ushort4*)&xin[i0 * FSTR + r * 4];
                ax += bf2f(u.x); ay += bf2f(u.y); az += bf2f(u.z); aw += bf2f(u.w);
            }
        }
        // reduce partial sums across the EPG lane groups
#pragma unroll
        for (int m = RL; m < 64; m <<= 1) {
            ax += __shfl_xor(ax, m, 64);
            ay += __shfl_xor(ay, m, 64);
            az += __shfl_xor(az, m, 64);
            aw += __shfl_xor(aw, m, 64);
        }
        if (g == 0) {
            ushort4 o;
            o.x = f2bf(ax); o.y = f2bf(ay); o.z = f2bf(az); o.w = f2bf(aw);
            *(ushort4*)&y[n * 64 + r * 4] = o;
        } else if (PADZ && g == 1) {
            ushort4 o; o.x = 0; o.y = 0; o.z = 0; o.w = 0;
            *(ushort4*)&y[n * 64 + 16 + r * 4] = o;
        }
    }
}

// ---------------- MFMA MLP: 16-node tile per wave --------------------------------------
// matmul1: acc[t] (16 nodes x 16 feats, t=0..3) = y_tile @ W1 via mfma_16x16x32_bf16.
// BN+relu in C layout; z -> per-wave LDS slice -> reload in A layout; matmul2; relu; store.
// A layout: lane holds m=lane&15, k=quad*8+j. C/D: col=lane&15, row=quad*4+reg.
template <int KC1>
__launch_bounds__(256)
__global__ void mlp_mfma_kernel(const unsigned short* __restrict__ ybf,
                                const unsigned short* __restrict__ wfrag,
                                const float* __restrict__ b1, const float* __restrict__ g,
                                const float* __restrict__ be, const float* __restrict__ m,
                                const float* __restrict__ v,  const float* __restrict__ b2,
                                unsigned short* __restrict__ hout) {
    __shared__ __align__(16) unsigned short zs[4][16 * 72];  // per-wave slice, padded stride
    int lane = threadIdx.x & 63;
    int wid = threadIdx.x >> 6;
    int quad = lane >> 4;
    int n16 = lane & 15;

    // preload weight fragments (B-operand) for this layer
    const bf16x8* wf = (const bf16x8*)wfrag;
    bf16x8 w1f[4][2], w2f[4][2];
#pragma unroll
    for (int t = 0; t < 4; ++t) {
#pragma unroll
        for (int c = 0; c < 2; ++c) {
            w1f[t][c] = wf[((0 * 4 + t) * 2 + c) * 64 + lane];
            w2f[t][c] = wf[((1 * 4 + t) * 2 + c) * 64 + lane];
        }
    }
    // per-lane BN/bias scalars for feature f = t*16 + n16
    float scaleF[4], shiftF[4], b2F[4];
#pragma unroll
    for (int t = 0; t < 4; ++t) {
        int f = t * 16 + n16;
        float sc = g[f] * rsqrtf(v[f] + BN_EPS);
        scaleF[t] = sc;
        shiftF[t] = (b1[f] - m[f]) * sc + be[f];
        b2F[t] = b2[f];
    }

    unsigned short* zrow = &zs[wid][0];
    int ntiles = gridDim.x * 4;
    for (int tile = blockIdx.x * 4 + wid; tile < NTILES; tile += ntiles) {
        int nodebase = tile * 16;
        const unsigned short* yrow = ybf + (size_t)(nodebase + n16) * 64 + quad * 8;
        bf16x8 a0 = *(const bf16x8*)yrow;
        bf16x8 a1 = (KC1 == 2) ? *(const bf16x8*)(yrow + 32) : a0;

        f32x4 acc[4];
#pragma unroll
        for (int t = 0; t < 4; ++t) {
            f32x4 z4 = {0.f, 0.f, 0.f, 0.f};
            z4 = __builtin_amdgcn_mfma_f32_16x16x32_bf16(a0, w1f[t][0], z4, 0, 0, 0);
            if (KC1 == 2)
                z4 = __builtin_amdgcn_mfma_f32_16x16x32_bf16(a1, w1f[t][1], z4, 0, 0, 0);
            acc[t] = z4;
        }
        // BN + relu, z tile -> LDS (bf16), row = node-in-tile, col = feature
#pragma unroll
        for (int t = 0; t < 4; ++t) {
#pragma unroll
            for (int r = 0; r < 4; ++r) {
                float z = fmaxf(fmaf(acc[t][r], scaleF[t], shiftF[t]), 0.f);
                zrow[(quad * 4 + r) * 72 + t * 16 + n16] = f2bf(z);
            }
        }
        __threadfence_block();  // drain ds writes (intra-wave; per-wave LDS slice)
        bf16x8 az0 = *(const bf16x8*)&zrow[n16 * 72 + quad * 8];
        bf16x8 az1 = *(const bf16x8*)&zrow[n16 * 72 + 32 + quad * 8];

        f32x4 acc2[4];
#pragma unroll
        for (int t = 0; t < 4; ++t) {
            f32x4 z4 = {0.f, 0.f, 0.f, 0.f};
            z4 = __builtin_amdgcn_mfma_f32_16x16x32_bf16(az0, w2f[t][0], z4, 0, 0, 0);
            z4 = __builtin_amdgcn_mfma_f32_16x16x32_bf16(az1, w2f[t][1], z4, 0, 0, 0);
            acc2[t] = z4;
        }
#pragma unroll
        for (int t = 0; t < 4; ++t) {
#pragma unroll
            for (int r = 0; r < 4; ++r) {
                float h = fmaxf(acc2[t][r] + b2F[t], 0.f);
                hout[(size_t)(nodebase + quad * 4 + r) * 64 + t * 16 + n16] = f2bf(h);
            }
        }
        __threadfence_block();  // reads done before next iter's writes (intra-wave order)
    }
}

// ---------------- pooling + FC head (block per graph; batch sorted -> range scan) -----
__global__ void pool_head_kernel(const unsigned short* __restrict__ h1,
                                 const unsigned short* __restrict__ h2,
                                 const unsigned short* __restrict__ h3,
                                 const int* __restrict__ batch,
                                 const float* __restrict__ fc1W, const float* __restrict__ fc1b,
                                 const float* __restrict__ fc2W, const float* __restrict__ fc2b,
                                 float* __restrict__ out) {
    __shared__ float ps[192];
    __shared__ float hs[192];
    __shared__ int bounds[2];
    int gi = blockIdx.x;
    int t = threadIdx.x;  // 192
    if (t < 2) {
        int target = gi + t;
        int lo = 0, hi = NNODES;
        while (lo < hi) {
            int mid = (lo + hi) >> 1;
            if (batch[mid] < target) lo = mid + 1; else hi = mid;
        }
        bounds[t] = lo;
    }
    __syncthreads();
    int nlo = bounds[0], nhi = bounds[1];
    const unsigned short* hb = (t < 64) ? h1 : (t < 128) ? h2 : h3;
    int f = t & 63;
    float s = 0.f;
    for (int n = nlo; n < nhi; ++n) s += bf2f(hb[n * 64 + f]);
    ps[t] = s;
    __syncthreads();
    float acc = fc1b[t];
#pragma unroll 8
    for (int k = 0; k < 192; ++k) acc = fmaf(ps[k], fc1W[k * 192 + t], acc);
    hs[t] = fmaxf(acc, 0.f);
    __syncthreads();
    if (t == 0) {
        float l0 = fc2b[0], l1 = fc2b[1];
        for (int k = 0; k < 192; ++k) {
            float h = hs[k];
            l0 = fmaf(h, fc2W[k * 2 + 0], l0);
            l1 = fmaf(h, fc2W[k * 2 + 1], l1);
        }
        float mx = fmaxf(l0, l1);
        float lse = mx + logf(expf(l0 - mx) + expf(l1 - mx));
        out[gi * 2 + 0] = l0 - lse;
        out[gi * 2 + 1] = l1 - lse;
    }
}

extern "C" void kernel_launch(void* const* d_in, const int* in_sizes, int n_in,
                              void* d_out, int out_size, void* d_ws, size_t ws_size,
                              hipStream_t stream) {
    const float* x = (const float*)d_in[0];
    const int* src = (const int*)d_in[1];
    const int* dst = (const int*)d_in[2];
    const int* batch = (const int*)d_in[3];
    const float* c1[8];
    const float* c2[8];
    const float* c3[8];
    for (int i = 0; i < 8; ++i) {
        c1[i] = (const float*)d_in[4 + i];
        c2[i] = (const float*)d_in[12 + i];
        c3[i] = (const float*)d_in[20 + i];
    }
    const float* fc1W = (const float*)d_in[28];
    const float* fc1b = (const float*)d_in[29];
    const float* fc2W = (const float*)d_in[30];
    const float* fc2b = (const float*)d_in[31];
    float* out = (float*)d_out;

    // ---- workspace layout (all bf16 activations) ----
    unsigned short* base = (unsigned short*)d_ws;
    const size_t NA = (size_t)NNODES * 64;
    unsigned short* ybf = base;                          // N*64
    unsigned short* xbf = ybf + NA;                      // N*16
    unsigned short* h1  = xbf + (size_t)NNODES * NFP;    // N*64
    unsigned short* h2  = h1 + NA;                       // N*64
    unsigned short* h3  = h2 + NA;                       // N*64
    unsigned short* wfrag = h3 + NA;                     // 3*8192 (16B-aligned)
    int* ibase = (int*)(wfrag + 3 * 8192);
    int* deg      = ibase;                    // N
    int* offsets  = ibase + NNODES;           // N+1
    int* cursor   = offsets + NNODES + 1;     // N
    int* csr      = cursor + NNODES;          // E
    int* partials = csr + NEDGES;             // NBLK

    hipMemsetAsync(deg, 0, (size_t)NNODES * sizeof(int), stream);

    // ---- build CSR by dst (once) + convert x to bf16 + weight fragments ----
    hist_kernel<<<4096, 256, 0, stream>>>(dst, deg);
    cvt_x_kernel<<<2048, 256, 0, stream>>>(x, xbf);
    build_frags_kernel<<<12, 256, 0, stream>>>(c1[0], c1[6], c2[0], c2[6], c3[0], c3[6], wfrag);
    partial_sum_kernel<<<NBLK, SCAN_BLK, 0, stream>>>(deg, partials);
    scan_partials_kernel<<<1, 512, 0, stream>>>(partials);
    scan_block_kernel<<<NBLK, SCAN_BLK, 0, stream>>>(deg, partials, offsets, cursor);
    build_csr_pass_kernel<<<NPASS * CPB, 256, 0, stream>>>(src, dst, cursor, csr);

    const int AGG_BLOCKS = 25000;  // 4 waves/block -> one wave per node
    const int MLP_BLOCKS = 1024;

    // ---- layer 1 (fin=13, 32 B rows): 16 edges/gather; MFMA MLP with K=32 (1 chunk) ----
    agg_vec_kernel<NFP, 4, 2, 1><<<AGG_BLOCKS, 256, 0, stream>>>(xbf, offsets, csr, ybf);
    mlp_mfma_kernel<1><<<MLP_BLOCKS, 256, 0, stream>>>(
        ybf, wfrag + 0 * 8192, c1[1], c1[2], c1[3], c1[4], c1[5], c1[7], h1);

    // ---- layer 2 (fin=64, 128 B rows): 4 edges/gather; MFMA MLP K=64 ----
    agg_vec_kernel<64, 16, 4, 0><<<AGG_BLOCKS, 256, 0, stream>>>(h1, offsets, csr, ybf);
    mlp_mfma_kernel<2><<<MLP_BLOCKS, 256, 0, stream>>>(
        ybf, wfrag + 1 * 8192, c2[1], c2[2], c2[3], c2[4], c2[5], c2[7], h2);

    // ---- layer 3 (fin=64) ----
    agg_vec_kernel<64, 16, 4, 0><<<AGG_BLOCKS, 256, 0, stream>>>(h2, offsets, csr, ybf);
    mlp_mfma_kernel<2><<<MLP_BLOCKS, 256, 0, stream>>>(
        ybf, wfrag + 2 * 8192, c3[1], c3[2], c3[3], c3[4], c3[5], c3[7], h3);

    // ---- pooling + FC head fused ----
    pool_head_kernel<<<NG, 192, 0, stream>>>(h1, h2, h3, batch, fc1W, fc1b, fc2W, fc2b, out);
}

// Round 8
// 682.077 us; speedup vs baseline: 3.3298x; 1.0015x over previous
//
#include <hip/hip_runtime.h>

#define NNODES 100000
#define NEDGES 3200000
#define NF 13
#define NFP 16       // padded bf16 row stride for x
#define NG 512
#define BN_EPS 1e-5f
#define NTILES (NNODES / 16)   // 6250 exactly

#define SCAN_BLK 256
#define NBLK ((NNODES + SCAN_BLK - 1) / SCAN_BLK)   // 391

#define NPASS 16
#define BUCKET (NNODES / NPASS)   // 6250 exactly
#define REGCAP 204800             // pairs per bucket region (mean 200k, sigma ~433)
#define PTILE 2048
#define NPBLK ((NEDGES + PTILE - 1) / PTILE)  // 1563

typedef __attribute__((ext_vector_type(8))) short bf16x8;
typedef __attribute__((ext_vector_type(4))) float f32x4;

__device__ __forceinline__ float bf2f(unsigned short u) {
    return __uint_as_float(((unsigned)u) << 16);
}
__device__ __forceinline__ unsigned short f2bf(float f) {
    unsigned u = __float_as_uint(f);
    unsigned r = (u + 0x7FFFu + ((u >> 16) & 1u)) >> 16;  // RNE
    return (unsigned short)r;
}

// ---------------- CSR build: histogram of dst ----------------
__global__ void hist_kernel(const int* __restrict__ dst, int* __restrict__ deg) {
    int idx = blockIdx.x * blockDim.x + threadIdx.x;
    int stride = gridDim.x * blockDim.x;
    for (int e = idx; e < NEDGES; e += stride) atomicAdd(&deg[dst[e]], 1);
}

// ---------------- per-block partial sums of deg ----------------
__global__ void partial_sum_kernel(const int* __restrict__ deg, int* __restrict__ partials) {
    __shared__ int s[SCAN_BLK];
    int t = threadIdx.x;
    int i = blockIdx.x * SCAN_BLK + t;
    s[t] = (i < NNODES) ? deg[i] : 0;
    __syncthreads();
    for (int off = SCAN_BLK / 2; off > 0; off >>= 1) {
        if (t < off) s[t] += s[t + off];
        __syncthreads();
    }
    if (t == 0) partials[blockIdx.x] = s[0];
}

// ---------------- exclusive scan of partials (single block, 512 >= NBLK) --------------
__global__ void scan_partials_kernel(int* __restrict__ partials) {
    __shared__ int s[512];
    int t = threadIdx.x;
    int v = (t < NBLK) ? partials[t] : 0;
    s[t] = v;
    __syncthreads();
    for (int off = 1; off < 512; off <<= 1) {
        int tmp = (t >= off) ? s[t - off] : 0;
        __syncthreads();
        s[t] += tmp;
        __syncthreads();
    }
    if (t < NBLK) partials[t] = s[t] - v;  // exclusive
}

// ---------------- per-block exclusive scan -> offsets, cursor ----------------
__global__ void scan_block_kernel(const int* __restrict__ deg, const int* __restrict__ partials,
                                  int* __restrict__ offsets, int* __restrict__ cursor) {
    __shared__ int s[SCAN_BLK];
    int t = threadIdx.x;
    int i = blockIdx.x * SCAN_BLK + t;
    int v = (i < NNODES) ? deg[i] : 0;
    s[t] = v;
    __syncthreads();
    for (int off = 1; off < SCAN_BLK; off <<= 1) {
        int tmp = (t >= off) ? s[t - off] : 0;
        __syncthreads();
        s[t] += tmp;
        __syncthreads();
    }
    if (i < NNODES) {
        int excl = partials[blockIdx.x] + s[t] - v;
        offsets[i] = excl;
        cursor[i] = excl;
    }
    if (i == 0) offsets[NNODES] = NEDGES;
}

// ---------------- phase A: partition edges into 16 dst-buckets (dense pair regions) ---
// One 2048-edge tile per block: LDS histogram -> reserve via 16 global atomics ->
// LDS bucket-sort -> coalesced write of (dst,src) pairs to bucket regions.
__launch_bounds__(256)
__global__ void partition_kernel(const int* __restrict__ src, const int* __restrict__ dst,
                                 int* __restrict__ gcount, int2* __restrict__ pairbuf) {
    __shared__ int lhist[16];
    __shared__ int lscan[16];   // exclusive start of bucket within tile
    __shared__ int lbase[16];   // global base reserved for this tile's bucket chunk
    __shared__ int lpos[16];
    __shared__ int2 stage[PTILE];
    int t = threadIdx.x;
    int base = blockIdx.x * PTILE;
    int cnt = NEDGES - base; if (cnt > PTILE) cnt = PTILE;

    int d[PTILE / 256], s[PTILE / 256], b[PTILE / 256];
#pragma unroll
    for (int j = 0; j < PTILE / 256; ++j) {
        int i = t + j * 256;
        if (i < cnt) {
            d[j] = __builtin_nontemporal_load(dst + base + i);
            s[j] = __builtin_nontemporal_load(src + base + i);
            b[j] = d[j] / BUCKET;
        } else b[j] = -1;
    }
    if (t < 16) lhist[t] = 0;
    __syncthreads();
#pragma unroll
    for (int j = 0; j < PTILE / 256; ++j)
        if (b[j] >= 0) atomicAdd(&lhist[b[j]], 1);
    __syncthreads();
    if (t == 0) {
        int run = 0;
        for (int k = 0; k < 16; ++k) { lscan[k] = run; run += lhist[k]; }
    }
    __syncthreads();
    if (t < 16) {
        lbase[t] = atomicAdd(&gcount[t], lhist[t]);
        lpos[t] = lscan[t];
    }
    __syncthreads();
#pragma unroll
    for (int j = 0; j < PTILE / 256; ++j) {
        if (b[j] >= 0) {
            int p = atomicAdd(&lpos[b[j]], 1);
            stage[p] = make_int2(d[j], s[j]);
        }
    }
    __syncthreads();
    for (int i = t; i < cnt; i += 256) {
        int bk = 0;
#pragma unroll
        for (int k = 1; k < 16; ++k) if (i >= lscan[k]) bk = k;
        pairbuf[(size_t)bk * REGCAP + lbase[bk] + (i - lscan[bk])] = stage[i];
    }
}

// ---------------- phase B: per-bucket scatter into csr (writes stay in 0.8 MB slice) --
#define CPB2 64
__global__ void bucket_scatter_kernel(const int2* __restrict__ pairbuf,
                                      const int* __restrict__ gcount,
                                      int* __restrict__ cursor, int* __restrict__ csr) {
    int bucket = blockIdx.x & 15;
    int chunk = blockIdx.x >> 4;     // [0, CPB2)
    int cnt = gcount[bucket];
    const int2* pb = pairbuf + (size_t)bucket * REGCAP;
    const int stride = CPB2 * 256;
    for (int i = chunk * 256 + threadIdx.x; i < cnt; i += stride) {
        int2 p = pb[i];
        int pos = atomicAdd(&cursor[p.x], 1);
        csr[pos] = p.y;
    }
}

// ---------------- convert x (fp32, stride 13) -> xbf (bf16, stride 16, zero-padded) ---
__global__ void cvt_x_kernel(const float* __restrict__ x, unsigned short* __restrict__ xbf) {
    const int total = NNODES * NFP;
    int idx = blockIdx.x * blockDim.x + threadIdx.x;
    int stride = gridDim.x * blockDim.x;
    for (int i = idx; i < total; i += stride) {
        int n = i >> 4;
        int f = i & 15;
        xbf[i] = (f < NF) ? f2bf(x[n * NF + f]) : (unsigned short)0;
    }
}

// ---------------- build MFMA B-fragments for all layer weights (bf16) ----------------
__global__ void build_frags_kernel(const float* __restrict__ w10, const float* __restrict__ w20,
                                   const float* __restrict__ w11, const float* __restrict__ w21,
                                   const float* __restrict__ w12, const float* __restrict__ w22,
                                   unsigned short* __restrict__ wfrag) {
    int tid = blockIdx.x * blockDim.x + threadIdx.x;  // 3072 total
    if (tid >= 3072) return;
    int layer = tid >> 10;
    int rem = tid & 1023;
    int mat = rem >> 9;
    int tile = (rem >> 7) & 3;
    int chunk = (rem >> 6) & 1;
    int lane = rem & 63;
    int quad = lane >> 4, n = lane & 15;
    const float* W = (layer == 0) ? (mat ? w20 : w10)
                   : (layer == 1) ? (mat ? w21 : w11)
                                  : (mat ? w22 : w12);
    int K = (layer == 0 && mat == 0) ? NF : 64;
    unsigned short* o = wfrag + ((size_t)tid) * 8;
#pragma unroll
    for (int j = 0; j < 8; ++j) {
        int k = chunk * 32 + quad * 8 + j;
        float val = (k < K) ? W[k * 64 + tile * 16 + n] : 0.f;
        o[j] = f2bf(val);
    }
}

// ---------------- vectorized bf16 aggregation ----------------
template <int FSTR, int RL, int UNROLL, int PADZ>
__launch_bounds__(256, 8)
__global__ void agg_vec_kernel(const unsigned short* __restrict__ xin,
                               const int* __restrict__ offsets,
                               const int* __restrict__ csr,
                               unsigned short* __restrict__ y) {
    const int EPG = 64 / RL;
    int lane = threadIdx.x & 63;
    int g = lane / RL;
    int r = lane % RL;
    int wave = (blockIdx.x * blockDim.x + threadIdx.x) >> 6;
    int nw = (gridDim.x * blockDim.x) >> 6;

    for (int n = wave; n < NNODES; n += nw) {
        int beg = offsets[n], end = offsets[n + 1];
        float ax = 0.f, ay = 0.f, az = 0.f, aw = 0.f;
        if (g == 0) {  // self row, added once
            ushort4 u = *(const ushort4*)&xin[n * FSTR + r * 4];
            ax = bf2f(u.x); ay = bf2f(u.y); az = bf2f(u.z); aw = bf2f(u.w);
        }
        int j = beg;
        const int STEP = UNROLL * EPG;
        for (; j + STEP <= end; j += STEP) {
#pragma unroll
            for (int t = 0; t < UNROLL; ++t) {
                int e = j + t * EPG + g;           // guaranteed < end
                int i0 = csr[e];
                ushort4 u = *(const ushort4*)&xin[i0 * FSTR + r * 4];
                ax += bf2f(u.x); ay += bf2f(u.y); az += bf2f(u.z); aw += bf2f(u.w);
            }
        }
        for (; j < end; j += EPG) {
            int e = j + g;
            if (e < end) {
                int i0 = csr[e];
                ushort4 u = *(const ushort4*)&xin[i0 * FSTR + r * 4];
                ax += bf2f(u.x); ay += bf2f(u.y); az += bf2f(u.z); aw += bf2f(u.w);
            }
        }
#pragma unroll
        for (int m = RL; m < 64; m <<= 1) {
            ax += __shfl_xor(ax, m, 64);
            ay += __shfl_xor(ay, m, 64);
            az += __shfl_xor(az, m, 64);
            aw += __shfl_xor(aw, m, 64);
        }
        if (g == 0) {
            ushort4 o;
            o.x = f2bf(ax); o.y = f2bf(ay); o.z = f2bf(az); o.w = f2bf(aw);
            *(ushort4*)&y[n * 64 + r * 4] = o;
        } else if (PADZ && g == 1) {
            ushort4 o; o.x = 0; o.y = 0; o.z = 0; o.w = 0;
            *(ushort4*)&y[n * 64 + 16 + r * 4] = o;
        }
    }
}

// ---------------- MFMA MLP: 16-node tile per wave --------------------------------------
template <int KC1>
__launch_bounds__(256)
__global__ void mlp_mfma_kernel(const unsigned short* __restrict__ ybf,
                                const unsigned short* __restrict__ wfrag,
                                const float* __restrict__ b1, const float* __restrict__ g,
                                const float* __restrict__ be, const float* __restrict__ m,
                                const float* __restrict__ v,  const float* __restrict__ b2,
                                unsigned short* __restrict__ hout) {
    __shared__ __align__(16) unsigned short zs[4][16 * 72];  // per-wave slice, padded stride
    int lane = threadIdx.x & 63;
    int wid = threadIdx.x >> 6;
    int quad = lane >> 4;
    int n16 = lane & 15;

    const bf16x8* wf = (const bf16x8*)wfrag;
    bf16x8 w1f[4][2], w2f[4][2];
#pragma unroll
    for (int t = 0; t < 4; ++t) {
#pragma unroll
        for (int c = 0; c < 2; ++c) {
            w1f[t][c] = wf[((0 * 4 + t) * 2 + c) * 64 + lane];
            w2f[t][c] = wf[((1 * 4 + t) * 2 + c) * 64 + lane];
        }
    }
    float scaleF[4], shiftF[4], b2F[4];
#pragma unroll
    for (int t = 0; t < 4; ++t) {
        int f = t * 16 + n16;
        float sc = g[f] * rsqrtf(v[f] + BN_EPS);
        scaleF[t] = sc;
        shiftF[t] = (b1[f] - m[f]) * sc + be[f];
        b2F[t] = b2[f];
    }

    unsigned short* zrow = &zs[wid][0];
    int ntiles = gridDim.x * 4;
    for (int tile = blockIdx.x * 4 + wid; tile < NTILES; tile += ntiles) {
        int nodebase = tile * 16;
        const unsigned short* yrow = ybf + (size_t)(nodebase + n16) * 64 + quad * 8;
        bf16x8 a0 = *(const bf16x8*)yrow;
        bf16x8 a1 = (KC1 == 2) ? *(const bf16x8*)(yrow + 32) : a0;

        f32x4 acc[4];
#pragma unroll
        for (int t = 0; t < 4; ++t) {
            f32x4 z4 = {0.f, 0.f, 0.f, 0.f};
            z4 = __builtin_amdgcn_mfma_f32_16x16x32_bf16(a0, w1f[t][0], z4, 0, 0, 0);
            if (KC1 == 2)
                z4 = __builtin_amdgcn_mfma_f32_16x16x32_bf16(a1, w1f[t][1], z4, 0, 0, 0);
            acc[t] = z4;
        }
#pragma unroll
        for (int t = 0; t < 4; ++t) {
#pragma unroll
            for (int r = 0; r < 4; ++r) {
                float z = fmaxf(fmaf(acc[t][r], scaleF[t], shiftF[t]), 0.f);
                zrow[(quad * 4 + r) * 72 + t * 16 + n16] = f2bf(z);
            }
        }
        __threadfence_block();
        bf16x8 az0 = *(const bf16x8*)&zrow[n16 * 72 + quad * 8];
        bf16x8 az1 = *(const bf16x8*)&zrow[n16 * 72 + 32 + quad * 8];

        f32x4 acc2[4];
#pragma unroll
        for (int t = 0; t < 4; ++t) {
            f32x4 z4 = {0.f, 0.f, 0.f, 0.f};
            z4 = __builtin_amdgcn_mfma_f32_16x16x32_bf16(az0, w2f[t][0], z4, 0, 0, 0);
            z4 = __builtin_amdgcn_mfma_f32_16x16x32_bf16(az1, w2f[t][1], z4, 0, 0, 0);
            acc2[t] = z4;
        }
#pragma unroll
        for (int t = 0; t < 4; ++t) {
#pragma unroll
            for (int r = 0; r < 4; ++r) {
                float h = fmaxf(acc2[t][r] + b2F[t], 0.f);
                hout[(size_t)(nodebase + quad * 4 + r) * 64 + t * 16 + n16] = f2bf(h);
            }
        }
        __threadfence_block();
    }
}

// ---------------- pooling + FC head (block per graph; batch sorted -> range scan) -----
__global__ void pool_head_kernel(const unsigned short* __restrict__ h1,
                                 const unsigned short* __restrict__ h2,
                                 const unsigned short* __restrict__ h3,
                                 const int* __restrict__ batch,
                                 const float* __restrict__ fc1W, const float* __restrict__ fc1b,
                                 const float* __restrict__ fc2W, const float* __restrict__ fc2b,
                                 float* __restrict__ out) {
    __shared__ float ps[192];
    __shared__ float hs[192];
    __shared__ int bounds[2];
    int gi = blockIdx.x;
    int t = threadIdx.x;  // 192
    if (t < 2) {
        int target = gi + t;
        int lo = 0, hi = NNODES;
        while (lo < hi) {
            int mid = (lo + hi) >> 1;
            if (batch[mid] < target) lo = mid + 1; else hi = mid;
        }
        bounds[t] = lo;
    }
    __syncthreads();
    int nlo = bounds[0], nhi = bounds[1];
    const unsigned short* hb = (t < 64) ? h1 : (t < 128) ? h2 : h3;
    int f = t & 63;
    float s = 0.f;
    for (int n = nlo; n < nhi; ++n) s += bf2f(hb[n * 64 + f]);
    ps[t] = s;
    __syncthreads();
    float acc = fc1b[t];
#pragma unroll 8
    for (int k = 0; k < 192; ++k) acc = fmaf(ps[k], fc1W[k * 192 + t], acc);
    hs[t] = fmaxf(acc, 0.f);
    __syncthreads();
    if (t == 0) {
        float l0 = fc2b[0], l1 = fc2b[1];
        for (int k = 0; k < 192; ++k) {
            float h = hs[k];
            l0 = fmaf(h, fc2W[k * 2 + 0], l0);
            l1 = fmaf(h, fc2W[k * 2 + 1], l1);
        }
        float mx = fmaxf(l0, l1);
        float lse = mx + logf(expf(l0 - mx) + expf(l1 - mx));
        out[gi * 2 + 0] = l0 - lse;
        out[gi * 2 + 1] = l1 - lse;
    }
}

extern "C" void kernel_launch(void* const* d_in, const int* in_sizes, int n_in,
                              void* d_out, int out_size, void* d_ws, size_t ws_size,
                              hipStream_t stream) {
    const float* x = (const float*)d_in[0];
    const int* src = (const int*)d_in[1];
    const int* dst = (const int*)d_in[2];
    const int* batch = (const int*)d_in[3];
    const float* c1[8];
    const float* c2[8];
    const float* c3[8];
    for (int i = 0; i < 8; ++i) {
        c1[i] = (const float*)d_in[4 + i];
        c2[i] = (const float*)d_in[12 + i];
        c3[i] = (const float*)d_in[20 + i];
    }
    const float* fc1W = (const float*)d_in[28];
    const float* fc1b = (const float*)d_in[29];
    const float* fc2W = (const float*)d_in[30];
    const float* fc2b = (const float*)d_in[31];
    float* out = (float*)d_out;

    // ---- workspace layout (all bf16 activations) ----
    unsigned short* base = (unsigned short*)d_ws;
    const size_t NA = (size_t)NNODES * 64;
    unsigned short* ybf = base;                          // N*64
    unsigned short* xbf = ybf + NA;                      // N*16
    unsigned short* h1  = xbf + (size_t)NNODES * NFP;    // N*64
    unsigned short* h2  = h1 + NA;                       // N*64
    unsigned short* h3  = h2 + NA;                       // N*64
    unsigned short* wfrag = h3 + NA;                     // 3*8192 (16B-aligned)
    int* ibase = (int*)(wfrag + 3 * 8192);
    int* deg      = ibase;                    // N
    int* gcount   = ibase + NNODES;           // 16 (zeroed with deg)
    int* offsets  = gcount + 16;              // N+1
    int* cursor   = offsets + NNODES + 1;     // N
    int* csr      = cursor + NNODES;          // E
    int* partials = csr + NEDGES;             // NBLK (+pad to even)
    int2* pairbuf = (int2*)(((uintptr_t)(partials + NBLK) + 15) & ~(uintptr_t)15); // 16*REGCAP

    hipMemsetAsync(deg, 0, (size_t)(NNODES + 16) * sizeof(int), stream);

    // ---- build CSR by dst (once) + convert x to bf16 + weight fragments ----
    hist_kernel<<<4096, 256, 0, stream>>>(dst, deg);
    cvt_x_kernel<<<2048, 256, 0, stream>>>(x, xbf);
    build_frags_kernel<<<12, 256, 0, stream>>>(c1[0], c1[6], c2[0], c2[6], c3[0], c3[6], wfrag);
    partition_kernel<<<NPBLK, 256, 0, stream>>>(src, dst, gcount, pairbuf);
    partial_sum_kernel<<<NBLK, SCAN_BLK, 0, stream>>>(deg, partials);
    scan_partials_kernel<<<1, 512, 0, stream>>>(partials);
    scan_block_kernel<<<NBLK, SCAN_BLK, 0, stream>>>(deg, partials, offsets, cursor);
    bucket_scatter_kernel<<<16 * CPB2, 256, 0, stream>>>(pairbuf, gcount, cursor, csr);

    const int AGG_BLOCKS = 25000;  // 4 waves/block -> one wave per node
    const int MLP_BLOCKS = 1024;

    // ---- layer 1 (fin=13, 32 B rows): 16 edges/gather; MFMA MLP with K=32 (1 chunk) ----
    agg_vec_kernel<NFP, 4, 2, 1><<<AGG_BLOCKS, 256, 0, stream>>>(xbf, offsets, csr, ybf);
    mlp_mfma_kernel<1><<<MLP_BLOCKS, 256, 0, stream>>>(
        ybf, wfrag + 0 * 8192, c1[1], c1[2], c1[3], c1[4], c1[5], c1[7], h1);

    // ---- layer 2 (fin=64, 128 B rows): 4 edges/gather; MFMA MLP K=64 ----
    agg_vec_kernel<64, 16, 4, 0><<<AGG_BLOCKS, 256, 0, stream>>>(h1, offsets, csr, ybf);
    mlp_mfma_kernel<2><<<MLP_BLOCKS, 256, 0, stream>>>(
        ybf, wfrag + 1 * 8192, c2[1], c2[2], c2[3], c2[4], c2[5], c2[7], h2);

    // ---- layer 3 (fin=64) ----
    agg_vec_kernel<64, 16, 4, 0><<<AGG_BLOCKS, 256, 0, stream>>>(h2, offsets, csr, ybf);
    mlp_mfma_kernel<2><<<MLP_BLOCKS, 256, 0, stream>>>(
        ybf, wfrag + 2 * 8192, c3[1], c3[2], c3[3], c3[4], c3[5], c3[7], h3);

    // ---- pooling + FC head fused ----
    pool_head_kernel<<<NG, 192, 0, stream>>>(h1, h2, h3, batch, fc1W, fc1b, fc2W, fc2b, out);
}

// Round 9
// 556.909 us; speedup vs baseline: 4.0782x; 1.2248x over previous
//
#include <hip/hip_runtime.h>

#define NNODES 100000
#define NEDGES 3200000
#define NF 13
#define NFP 16       // padded bf16 row stride for x
#define NG 512
#define BN_EPS 1e-5f
#define NTILES (NNODES / 16)   // 6250 exactly
#define CAP 80       // padded CSR slots per node (deg ~ Poisson(32); P(deg>=80) ~ 1e-11)

#define NPASS 16
#define BUCKET (NNODES / NPASS)   // 6250 exactly
#define CPB 128                   // blocks per pass; grid = NPASS*CPB = 2048

typedef __attribute__((ext_vector_type(8))) short bf16x8;
typedef __attribute__((ext_vector_type(4))) float f32x4;

__device__ __forceinline__ float bf2f(unsigned short u) {
    return __uint_as_float(((unsigned)u) << 16);
}
__device__ __forceinline__ unsigned short f2bf(float f) {
    unsigned u = __float_as_uint(f);
    unsigned r = (u + 0x7FFFu + ((u >> 16) & 1u)) >> 16;  // RNE
    return (unsigned short)r;
}

// ---------------- init padded-CSR cursors: cursor[n] = n*CAP ----------------
__global__ void init_cursor_kernel(int* __restrict__ cursor) {
    int i = blockIdx.x * blockDim.x + threadIdx.x;
    if (i < NNODES) cursor[i] = i * CAP;
}

// ---------------- bucketed CSR scatter into padded slots; NT edge reads ---------------
// 16 dst-range passes in one launch; each pass's csr writes confined to a 2 MB slice
// (stays in one L2, lines fill before writeback). No offsets/scan needed: slot base
// is n*CAP, final cursor[n] marks the end.
__global__ void build_csr_pass_kernel(const int* __restrict__ src, const int* __restrict__ dst,
                                      int* __restrict__ cursor, int* __restrict__ csr) {
    int pass = blockIdx.x & (NPASS - 1);
    int chunk = blockIdx.x >> 4;              // [0, CPB)
    int lo = pass * BUCKET, hi = lo + BUCKET;
    int e = chunk * blockDim.x + threadIdx.x;
    const int stride = CPB * 256;
    for (; e < NEDGES; e += stride) {
        int d = __builtin_nontemporal_load(dst + e);
        if (d >= lo && d < hi) {
            int s = __builtin_nontemporal_load(src + e);
            int p = atomicAdd(&cursor[d], 1);
            csr[p] = s;
        }
    }
}

// ---------------- convert x (fp32, stride 13) -> xbf (bf16, stride 16, zero-padded) ---
__global__ void cvt_x_kernel(const float* __restrict__ x, unsigned short* __restrict__ xbf) {
    const int total = NNODES * NFP;
    int idx = blockIdx.x * blockDim.x + threadIdx.x;
    int stride = gridDim.x * blockDim.x;
    for (int i = idx; i < total; i += stride) {
        int n = i >> 4;
        int f = i & 15;
        xbf[i] = (f < NF) ? f2bf(x[n * NF + f]) : (unsigned short)0;
    }
}

// ---------------- build MFMA B-fragments for all layer weights (bf16) ----------------
__global__ void build_frags_kernel(const float* __restrict__ w10, const float* __restrict__ w20,
                                   const float* __restrict__ w11, const float* __restrict__ w21,
                                   const float* __restrict__ w12, const float* __restrict__ w22,
                                   unsigned short* __restrict__ wfrag) {
    int tid = blockIdx.x * blockDim.x + threadIdx.x;  // 3072 total
    if (tid >= 3072) return;
    int layer = tid >> 10;
    int rem = tid & 1023;
    int mat = rem >> 9;
    int tile = (rem >> 7) & 3;
    int chunk = (rem >> 6) & 1;
    int lane = rem & 63;
    int quad = lane >> 4, n = lane & 15;
    const float* W = (layer == 0) ? (mat ? w20 : w10)
                   : (layer == 1) ? (mat ? w21 : w11)
                                  : (mat ? w22 : w12);
    int K = (layer == 0 && mat == 0) ? NF : 64;
    unsigned short* o = wfrag + ((size_t)tid) * 8;
#pragma unroll
    for (int j = 0; j < 8; ++j) {
        int k = chunk * 32 + quad * 8 + j;
        float val = (k < K) ? W[k * 64 + tile * 16 + n] : 0.f;
        o[j] = f2bf(val);
    }
}

// ---------------- vectorized bf16 aggregation (padded CSR) ----------------
// One wave per node. RL lanes x ushort4 cover one row; one gather fetches 64/RL rows.
template <int FSTR, int RL, int UNROLL, int PADZ>
__launch_bounds__(256, 8)
__global__ void agg_vec_kernel(const unsigned short* __restrict__ xin,
                               const int* __restrict__ cursor,
                               const int* __restrict__ csr,
                               unsigned short* __restrict__ y) {
    const int EPG = 64 / RL;
    int lane = threadIdx.x & 63;
    int g = lane / RL;
    int r = lane % RL;
    int wave = (blockIdx.x * blockDim.x + threadIdx.x) >> 6;
    int nw = (gridDim.x * blockDim.x) >> 6;

    for (int n = wave; n < NNODES; n += nw) {
        int beg = n * CAP;
        int end = cursor[n];
        float ax = 0.f, ay = 0.f, az = 0.f, aw = 0.f;
        if (g == 0) {  // self row, added once
            ushort4 u = *(const ushort4*)&xin[n * FSTR + r * 4];
            ax = bf2f(u.x); ay = bf2f(u.y); az = bf2f(u.z); aw = bf2f(u.w);
        }
        int j = beg;
        const int STEP = UNROLL * EPG;
        for (; j + STEP <= end; j += STEP) {
#pragma unroll
            for (int t = 0; t < UNROLL; ++t) {
                int e = j + t * EPG + g;           // guaranteed < end
                int i0 = csr[e];
                ushort4 u = *(const ushort4*)&xin[i0 * FSTR + r * 4];
                ax += bf2f(u.x); ay += bf2f(u.y); az += bf2f(u.z); aw += bf2f(u.w);
            }
        }
        for (; j < end; j += EPG) {
            int e = j + g;
            if (e < end) {
                int i0 = csr[e];
                ushort4 u = *(const ushort4*)&xin[i0 * FSTR + r * 4];
                ax += bf2f(u.x); ay += bf2f(u.y); az += bf2f(u.z); aw += bf2f(u.w);
            }
        }
#pragma unroll
        for (int m = RL; m < 64; m <<= 1) {
            ax += __shfl_xor(ax, m, 64);
            ay += __shfl_xor(ay, m, 64);
            az += __shfl_xor(az, m, 64);
            aw += __shfl_xor(aw, m, 64);
        }
        if (g == 0) {
            ushort4 o;
            o.x = f2bf(ax); o.y = f2bf(ay); o.z = f2bf(az); o.w = f2bf(aw);
            *(ushort4*)&y[n * 64 + r * 4] = o;
        } else if (PADZ && g == 1) {
            ushort4 o; o.x = 0; o.y = 0; o.z = 0; o.w = 0;
            *(ushort4*)&y[n * 64 + 16 + r * 4] = o;
        }
    }
}

// ---------------- MFMA MLP: 16-node tile per wave --------------------------------------
template <int KC1>
__launch_bounds__(256)
__global__ void mlp_mfma_kernel(const unsigned short* __restrict__ ybf,
                                const unsigned short* __restrict__ wfrag,
                                const float* __restrict__ b1, const float* __restrict__ g,
                                const float* __restrict__ be, const float* __restrict__ m,
                                const float* __restrict__ v,  const float* __restrict__ b2,
                                unsigned short* __restrict__ hout) {
    __shared__ __align__(16) unsigned short zs[4][16 * 72];  // per-wave slice, padded stride
    int lane = threadIdx.x & 63;
    int wid = threadIdx.x >> 6;
    int quad = lane >> 4;
    int n16 = lane & 15;

    const bf16x8* wf = (const bf16x8*)wfrag;
    bf16x8 w1f[4][2], w2f[4][2];
#pragma unroll
    for (int t = 0; t < 4; ++t) {
#pragma unroll
        for (int c = 0; c < 2; ++c) {
            w1f[t][c] = wf[((0 * 4 + t) * 2 + c) * 64 + lane];
            w2f[t][c] = wf[((1 * 4 + t) * 2 + c) * 64 + lane];
        }
    }
    float scaleF[4], shiftF[4], b2F[4];
#pragma unroll
    for (int t = 0; t < 4; ++t) {
        int f = t * 16 + n16;
        float sc = g[f] * rsqrtf(v[f] + BN_EPS);
        scaleF[t] = sc;
        shiftF[t] = (b1[f] - m[f]) * sc + be[f];
        b2F[t] = b2[f];
    }

    unsigned short* zrow = &zs[wid][0];
    int ntiles = gridDim.x * 4;
    for (int tile = blockIdx.x * 4 + wid; tile < NTILES; tile += ntiles) {
        int nodebase = tile * 16;
        const unsigned short* yrow = ybf + (size_t)(nodebase + n16) * 64 + quad * 8;
        bf16x8 a0 = *(const bf16x8*)yrow;
        bf16x8 a1 = (KC1 == 2) ? *(const bf16x8*)(yrow + 32) : a0;

        f32x4 acc[4];
#pragma unroll
        for (int t = 0; t < 4; ++t) {
            f32x4 z4 = {0.f, 0.f, 0.f, 0.f};
            z4 = __builtin_amdgcn_mfma_f32_16x16x32_bf16(a0, w1f[t][0], z4, 0, 0, 0);
            if (KC1 == 2)
                z4 = __builtin_amdgcn_mfma_f32_16x16x32_bf16(a1, w1f[t][1], z4, 0, 0, 0);
            acc[t] = z4;
        }
#pragma unroll
        for (int t = 0; t < 4; ++t) {
#pragma unroll
            for (int r = 0; r < 4; ++r) {
                float z = fmaxf(fmaf(acc[t][r], scaleF[t], shiftF[t]), 0.f);
                zrow[(quad * 4 + r) * 72 + t * 16 + n16] = f2bf(z);
            }
        }
        __threadfence_block();
        bf16x8 az0 = *(const bf16x8*)&zrow[n16 * 72 + quad * 8];
        bf16x8 az1 = *(const bf16x8*)&zrow[n16 * 72 + 32 + quad * 8];

        f32x4 acc2[4];
#pragma unroll
        for (int t = 0; t < 4; ++t) {
            f32x4 z4 = {0.f, 0.f, 0.f, 0.f};
            z4 = __builtin_amdgcn_mfma_f32_16x16x32_bf16(az0, w2f[t][0], z4, 0, 0, 0);
            z4 = __builtin_amdgcn_mfma_f32_16x16x32_bf16(az1, w2f[t][1], z4, 0, 0, 0);
            acc2[t] = z4;
        }
#pragma unroll
        for (int t = 0; t < 4; ++t) {
#pragma unroll
            for (int r = 0; r < 4; ++r) {
                float h = fmaxf(acc2[t][r] + b2F[t], 0.f);
                hout[(size_t)(nodebase + quad * 4 + r) * 64 + t * 16 + n16] = f2bf(h);
            }
        }
        __threadfence_block();
    }
}

// ---------------- pooling + FC head (block per graph; batch sorted -> range scan) -----
__global__ void pool_head_kernel(const unsigned short* __restrict__ h1,
                                 const unsigned short* __restrict__ h2,
                                 const unsigned short* __restrict__ h3,
                                 const int* __restrict__ batch,
                                 const float* __restrict__ fc1W, const float* __restrict__ fc1b,
                                 const float* __restrict__ fc2W, const float* __restrict__ fc2b,
                                 float* __restrict__ out) {
    __shared__ float ps[192];
    __shared__ float hs[192];
    __shared__ int bounds[2];
    int gi = blockIdx.x;
    int t = threadIdx.x;  // 192
    if (t < 2) {
        int target = gi + t;
        int lo = 0, hi = NNODES;
        while (lo < hi) {
            int mid = (lo + hi) >> 1;
            if (batch[mid] < target) lo = mid + 1; else hi = mid;
        }
        bounds[t] = lo;
    }
    __syncthreads();
    int nlo = bounds[0], nhi = bounds[1];
    const unsigned short* hb = (t < 64) ? h1 : (t < 128) ? h2 : h3;
    int f = t & 63;
    float s = 0.f;
    for (int n = nlo; n < nhi; ++n) s += bf2f(hb[n * 64 + f]);
    ps[t] = s;
    __syncthreads();
    float acc = fc1b[t];
#pragma unroll 8
    for (int k = 0; k < 192; ++k) acc = fmaf(ps[k], fc1W[k * 192 + t], acc);
    hs[t] = fmaxf(acc, 0.f);
    __syncthreads();
    if (t == 0) {
        float l0 = fc2b[0], l1 = fc2b[1];
        for (int k = 0; k < 192; ++k) {
            float h = hs[k];
            l0 = fmaf(h, fc2W[k * 2 + 0], l0);
            l1 = fmaf(h, fc2W[k * 2 + 1], l1);
        }
        float mx = fmaxf(l0, l1);
        float lse = mx + logf(expf(l0 - mx) + expf(l1 - mx));
        out[gi * 2 + 0] = l0 - lse;
        out[gi * 2 + 1] = l1 - lse;
    }
}

extern "C" void kernel_launch(void* const* d_in, const int* in_sizes, int n_in,
                              void* d_out, int out_size, void* d_ws, size_t ws_size,
                              hipStream_t stream) {
    const float* x = (const float*)d_in[0];
    const int* src = (const int*)d_in[1];
    const int* dst = (const int*)d_in[2];
    const int* batch = (const int*)d_in[3];
    const float* c1[8];
    const float* c2[8];
    const float* c3[8];
    for (int i = 0; i < 8; ++i) {
        c1[i] = (const float*)d_in[4 + i];
        c2[i] = (const float*)d_in[12 + i];
        c3[i] = (const float*)d_in[20 + i];
    }
    const float* fc1W = (const float*)d_in[28];
    const float* fc1b = (const float*)d_in[29];
    const float* fc2W = (const float*)d_in[30];
    const float* fc2b = (const float*)d_in[31];
    float* out = (float*)d_out;

    // ---- workspace layout (all bf16 activations) ----
    unsigned short* base = (unsigned short*)d_ws;
    const size_t NA = (size_t)NNODES * 64;
    unsigned short* ybf = base;                          // N*64
    unsigned short* xbf = ybf + NA;                      // N*16
    unsigned short* h1  = xbf + (size_t)NNODES * NFP;    // N*64
    unsigned short* h2  = h1 + NA;                       // N*64
    unsigned short* h3  = h2 + NA;                       // N*64
    unsigned short* wfrag = h3 + NA;                     // 3*8192 (16B-aligned)
    int* ibase = (int*)(wfrag + 3 * 8192);
    int* cursor = ibase;                      // N
    int* csr    = ibase + NNODES;             // N*CAP padded slots

    // ---- build padded CSR (no hist/scan) + convert x to bf16 + weight fragments ----
    init_cursor_kernel<<<(NNODES + 255) / 256, 256, 0, stream>>>(cursor);
    cvt_x_kernel<<<2048, 256, 0, stream>>>(x, xbf);
    build_frags_kernel<<<12, 256, 0, stream>>>(c1[0], c1[6], c2[0], c2[6], c3[0], c3[6], wfrag);
    build_csr_pass_kernel<<<NPASS * CPB, 256, 0, stream>>>(src, dst, cursor, csr);

    const int AGG_BLOCKS = 25000;  // 4 waves/block -> one wave per node
    const int MLP_BLOCKS = 1024;

    // ---- layer 1 (fin=13, 32 B rows): 16 edges/gather; MFMA MLP with K=32 (1 chunk) ----
    agg_vec_kernel<NFP, 4, 2, 1><<<AGG_BLOCKS, 256, 0, stream>>>(xbf, cursor, csr, ybf);
    mlp_mfma_kernel<1><<<MLP_BLOCKS, 256, 0, stream>>>(
        ybf, wfrag + 0 * 8192, c1[1], c1[2], c1[3], c1[4], c1[5], c1[7], h1);

    // ---- layer 2 (fin=64, 128 B rows): 4 edges/gather; MFMA MLP K=64 ----
    agg_vec_kernel<64, 16, 4, 0><<<AGG_BLOCKS, 256, 0, stream>>>(h1, cursor, csr, ybf);
    mlp_mfma_kernel<2><<<MLP_BLOCKS, 256, 0, stream>>>(
        ybf, wfrag + 1 * 8192, c2[1], c2[2], c2[3], c2[4], c2[5], c2[7], h2);

    // ---- layer 3 (fin=64) ----
    agg_vec_kernel<64, 16, 4, 0><<<AGG_BLOCKS, 256, 0, stream>>>(h2, cursor, csr, ybf);
    mlp_mfma_kernel<2><<<MLP_BLOCKS, 256, 0, stream>>>(
        ybf, wfrag + 2 * 8192, c3[1], c3[2], c3[3], c3[4], c3[5], c3[7], h3);

    // ---- pooling + FC head fused ----
    pool_head_kernel<<<NG, 192, 0, stream>>>(h1, h2, h3, batch, fc1W, fc1b, fc2W, fc2b, out);
}

// Round 10
// 452.267 us; speedup vs baseline: 5.0218x; 1.2314x over previous
//
#include <hip/hip_runtime.h>

#define NNODES 100000
#define NEDGES 3200000
#define NF 13
#define NFP 16       // padded bf16 row stride for x
#define NG 512
#define BN_EPS 1e-5f
#define NTILES (NNODES / 16)   // 6250 exactly
#define CAP 72       // padded CSR slots per node (deg ~ Poisson(32); P(deg>72) ~ 1e-9)

#define BSH 9                          // bucket = 512 dst nodes
#define NBUCK ((NNODES + 511) / 512)   // 196
#define RCAP 18500                     // pairs per bucket (mean 16384, sigma ~128)
#define PTILE 4096
#define NPBLK ((NEDGES + PTILE - 1) / PTILE)  // 782

typedef __attribute__((ext_vector_type(8))) short bf16x8;
typedef __attribute__((ext_vector_type(4))) float f32x4;

__device__ __forceinline__ float bf2f(unsigned short u) {
    return __uint_as_float(((unsigned)u) << 16);
}
__device__ __forceinline__ unsigned short f2bf(float f) {
    unsigned u = __float_as_uint(f);
    unsigned r = (u + 0x7FFFu + ((u >> 16) & 1u)) >> 16;  // RNE
    return (unsigned short)r;
}

// ---------------- phase A: partition edges into 196 buckets of 512 dst nodes ----------
// Packed entry: (d_local << 17) | src  (src < 2^17, d_local < 2^9). LDS histogram ->
// 196 reserve atomics per 4096-edge tile -> dense per-bucket writes.
__launch_bounds__(256)
__global__ void partition_kernel(const int* __restrict__ src, const int* __restrict__ dst,
                                 int* __restrict__ gcount, int* __restrict__ pairbuf) {
    __shared__ int lhist[NBUCK];
    __shared__ int lbase[NBUCK];
    __shared__ int lpos[NBUCK];
    int t = threadIdx.x;
    int base = blockIdx.x * PTILE;
    int cnt = NEDGES - base; if (cnt > PTILE) cnt = PTILE;

    int v[PTILE / 256], b[PTILE / 256];
#pragma unroll
    for (int j = 0; j < PTILE / 256; ++j) {
        int i = t + j * 256;
        if (i < cnt) {
            int d = __builtin_nontemporal_load(dst + base + i);
            int s = __builtin_nontemporal_load(src + base + i);
            b[j] = d >> BSH;
            v[j] = ((d & 511) << 17) | s;
        } else b[j] = -1;
    }
    if (t < NBUCK) lhist[t] = 0;
    __syncthreads();
#pragma unroll
    for (int j = 0; j < PTILE / 256; ++j)
        if (b[j] >= 0) atomicAdd(&lhist[b[j]], 1);
    __syncthreads();
    if (t < NBUCK) {
        lbase[t] = atomicAdd(&gcount[t], lhist[t]);
        lpos[t] = 0;
    }
    __syncthreads();
#pragma unroll
    for (int j = 0; j < PTILE / 256; ++j) {
        if (b[j] >= 0) {
            int p = atomicAdd(&lpos[b[j]], 1);
            pairbuf[(size_t)b[j] * RCAP + lbase[b[j]] + p] = v[j];
        }
    }
}

// ---------------- phase B: per-bucket scatter with LDS cursors ----------------
// One workgroup per bucket: per-node counts in LDS (3.2M LDS atomics instead of
// global), scatter into the bucket's 144 KB csr slice, then publish cursors.
__launch_bounds__(512)
__global__ void bucket_scatter_kernel(const int* __restrict__ pairbuf,
                                      const int* __restrict__ gcount,
                                      int* __restrict__ cursor, int* __restrict__ csr) {
    __shared__ int lcnt[512];
    int bk = blockIdx.x;
    int lo = bk << BSH;
    int cnt = gcount[bk];
    if (threadIdx.x < 512) lcnt[threadIdx.x] = 0;
    __syncthreads();
    const int* pb = pairbuf + (size_t)bk * RCAP;
    for (int i = threadIdx.x; i < cnt; i += 512) {
        int p = pb[i];
        int s = p & 0x1FFFF;
        int dl = p >> 17;
        int pos = atomicAdd(&lcnt[dl], 1);
        csr[(size_t)(lo + dl) * CAP + pos] = s;
    }
    __syncthreads();
    int n = lo + threadIdx.x;
    if (threadIdx.x < 512 && n < NNODES) cursor[n] = n * CAP + lcnt[threadIdx.x];
}

// ---------------- convert x (fp32, stride 13) -> xbf (bf16, stride 16, zero-padded) ---
__global__ void cvt_x_kernel(const float* __restrict__ x, unsigned short* __restrict__ xbf) {
    const int total = NNODES * NFP;
    int idx = blockIdx.x * blockDim.x + threadIdx.x;
    int stride = gridDim.x * blockDim.x;
    for (int i = idx; i < total; i += stride) {
        int n = i >> 4;
        int f = i & 15;
        xbf[i] = (f < NF) ? f2bf(x[n * NF + f]) : (unsigned short)0;
    }
}

// ---------------- build MFMA B-fragments for all layer weights (bf16) ----------------
__global__ void build_frags_kernel(const float* __restrict__ w10, const float* __restrict__ w20,
                                   const float* __restrict__ w11, const float* __restrict__ w21,
                                   const float* __restrict__ w12, const float* __restrict__ w22,
                                   unsigned short* __restrict__ wfrag) {
    int tid = blockIdx.x * blockDim.x + threadIdx.x;  // 3072 total
    if (tid >= 3072) return;
    int layer = tid >> 10;
    int rem = tid & 1023;
    int mat = rem >> 9;
    int tile = (rem >> 7) & 3;
    int chunk = (rem >> 6) & 1;
    int lane = rem & 63;
    int quad = lane >> 4, n = lane & 15;
    const float* W = (layer == 0) ? (mat ? w20 : w10)
                   : (layer == 1) ? (mat ? w21 : w11)
                                  : (mat ? w22 : w12);
    int K = (layer == 0 && mat == 0) ? NF : 64;
    unsigned short* o = wfrag + ((size_t)tid) * 8;
#pragma unroll
    for (int j = 0; j < 8; ++j) {
        int k = chunk * 32 + quad * 8 + j;
        float val = (k < K) ? W[k * 64 + tile * 16 + n] : 0.f;
        o[j] = f2bf(val);
    }
}

// ---------------- vectorized bf16 aggregation (padded CSR) ----------------
template <int FSTR, int RL, int UNROLL, int PADZ>
__launch_bounds__(256, 8)
__global__ void agg_vec_kernel(const unsigned short* __restrict__ xin,
                               const int* __restrict__ cursor,
                               const int* __restrict__ csr,
                               unsigned short* __restrict__ y) {
    const int EPG = 64 / RL;
    int lane = threadIdx.x & 63;
    int g = lane / RL;
    int r = lane % RL;
    int wave = (blockIdx.x * blockDim.x + threadIdx.x) >> 6;
    int nw = (gridDim.x * blockDim.x) >> 6;

    for (int n = wave; n < NNODES; n += nw) {
        int beg = n * CAP;
        int end = cursor[n];
        float ax = 0.f, ay = 0.f, az = 0.f, aw = 0.f;
        if (g == 0) {  // self row, added once
            ushort4 u = *(const ushort4*)&xin[n * FSTR + r * 4];
            ax = bf2f(u.x); ay = bf2f(u.y); az = bf2f(u.z); aw = bf2f(u.w);
        }
        int j = beg;
        const int STEP = UNROLL * EPG;
        for (; j + STEP <= end; j += STEP) {
#pragma unroll
            for (int t = 0; t < UNROLL; ++t) {
                int e = j + t * EPG + g;           // guaranteed < end
                int i0 = csr[e];
                ushort4 u = *(const ushort4*)&xin[i0 * FSTR + r * 4];
                ax += bf2f(u.x); ay += bf2f(u.y); az += bf2f(u.z); aw += bf2f(u.w);
            }
        }
        for (; j < end; j += EPG) {
            int e = j + g;
            if (e < end) {
                int i0 = csr[e];
                ushort4 u = *(const ushort4*)&xin[i0 * FSTR + r * 4];
                ax += bf2f(u.x); ay += bf2f(u.y); az += bf2f(u.z); aw += bf2f(u.w);
            }
        }
#pragma unroll
        for (int m = RL; m < 64; m <<= 1) {
            ax += __shfl_xor(ax, m, 64);
            ay += __shfl_xor(ay, m, 64);
            az += __shfl_xor(az, m, 64);
            aw += __shfl_xor(aw, m, 64);
        }
        if (g == 0) {
            ushort4 o;
            o.x = f2bf(ax); o.y = f2bf(ay); o.z = f2bf(az); o.w = f2bf(aw);
            *(ushort4*)&y[n * 64 + r * 4] = o;
        } else if (PADZ && g == 1) {
            ushort4 o; o.x = 0; o.y = 0; o.z = 0; o.w = 0;
            *(ushort4*)&y[n * 64 + 16 + r * 4] = o;
        }
    }
}

// ---------------- MFMA MLP: 16-node tile per wave --------------------------------------
template <int KC1>
__launch_bounds__(256)
__global__ void mlp_mfma_kernel(const unsigned short* __restrict__ ybf,
                                const unsigned short* __restrict__ wfrag,
                                const float* __restrict__ b1, const float* __restrict__ g,
                                const float* __restrict__ be, const float* __restrict__ m,
                                const float* __restrict__ v,  const float* __restrict__ b2,
                                unsigned short* __restrict__ hout) {
    __shared__ __align__(16) unsigned short zs[4][16 * 72];  // per-wave slice, padded stride
    int lane = threadIdx.x & 63;
    int wid = threadIdx.x >> 6;
    int quad = lane >> 4;
    int n16 = lane & 15;

    const bf16x8* wf = (const bf16x8*)wfrag;
    bf16x8 w1f[4][2], w2f[4][2];
#pragma unroll
    for (int t = 0; t < 4; ++t) {
#pragma unroll
        for (int c = 0; c < 2; ++c) {
            w1f[t][c] = wf[((0 * 4 + t) * 2 + c) * 64 + lane];
            w2f[t][c] = wf[((1 * 4 + t) * 2 + c) * 64 + lane];
        }
    }
    float scaleF[4], shiftF[4], b2F[4];
#pragma unroll
    for (int t = 0; t < 4; ++t) {
        int f = t * 16 + n16;
        float sc = g[f] * rsqrtf(v[f] + BN_EPS);
        scaleF[t] = sc;
        shiftF[t] = (b1[f] - m[f]) * sc + be[f];
        b2F[t] = b2[f];
    }

    unsigned short* zrow = &zs[wid][0];
    int ntiles = gridDim.x * 4;
    for (int tile = blockIdx.x * 4 + wid; tile < NTILES; tile += ntiles) {
        int nodebase = tile * 16;
        const unsigned short* yrow = ybf + (size_t)(nodebase + n16) * 64 + quad * 8;
        bf16x8 a0 = *(const bf16x8*)yrow;
        bf16x8 a1 = (KC1 == 2) ? *(const bf16x8*)(yrow + 32) : a0;

        f32x4 acc[4];
#pragma unroll
        for (int t = 0; t < 4; ++t) {
            f32x4 z4 = {0.f, 0.f, 0.f, 0.f};
            z4 = __builtin_amdgcn_mfma_f32_16x16x32_bf16(a0, w1f[t][0], z4, 0, 0, 0);
            if (KC1 == 2)
                z4 = __builtin_amdgcn_mfma_f32_16x16x32_bf16(a1, w1f[t][1], z4, 0, 0, 0);
            acc[t] = z4;
        }
#pragma unroll
        for (int t = 0; t < 4; ++t) {
#pragma unroll
            for (int r = 0; r < 4; ++r) {
                float z = fmaxf(fmaf(acc[t][r], scaleF[t], shiftF[t]), 0.f);
                zrow[(quad * 4 + r) * 72 + t * 16 + n16] = f2bf(z);
            }
        }
        __threadfence_block();
        bf16x8 az0 = *(const bf16x8*)&zrow[n16 * 72 + quad * 8];
        bf16x8 az1 = *(const bf16x8*)&zrow[n16 * 72 + 32 + quad * 8];

        f32x4 acc2[4];
#pragma unroll
        for (int t = 0; t < 4; ++t) {
            f32x4 z4 = {0.f, 0.f, 0.f, 0.f};
            z4 = __builtin_amdgcn_mfma_f32_16x16x32_bf16(az0, w2f[t][0], z4, 0, 0, 0);
            z4 = __builtin_amdgcn_mfma_f32_16x16x32_bf16(az1, w2f[t][1], z4, 0, 0, 0);
            acc2[t] = z4;
        }
#pragma unroll
        for (int t = 0; t < 4; ++t) {
#pragma unroll
            for (int r = 0; r < 4; ++r) {
                float h = fmaxf(acc2[t][r] + b2F[t], 0.f);
                hout[(size_t)(nodebase + quad * 4 + r) * 64 + t * 16 + n16] = f2bf(h);
            }
        }
        __threadfence_block();
    }
}

// ---------------- pooling + FC head (block per graph; batch sorted -> range scan) -----
__global__ void pool_head_kernel(const unsigned short* __restrict__ h1,
                                 const unsigned short* __restrict__ h2,
                                 const unsigned short* __restrict__ h3,
                                 const int* __restrict__ batch,
                                 const float* __restrict__ fc1W, const float* __restrict__ fc1b,
                                 const float* __restrict__ fc2W, const float* __restrict__ fc2b,
                                 float* __restrict__ out) {
    __shared__ float ps[192];
    __shared__ float hs[192];
    __shared__ int bounds[2];
    int gi = blockIdx.x;
    int t = threadIdx.x;  // 192
    if (t < 2) {
        int target = gi + t;
        int lo = 0, hi = NNODES;
        while (lo < hi) {
            int mid = (lo + hi) >> 1;
            if (batch[mid] < target) lo = mid + 1; else hi = mid;
        }
        bounds[t] = lo;
    }
    __syncthreads();
    int nlo = bounds[0], nhi = bounds[1];
    const unsigned short* hb = (t < 64) ? h1 : (t < 128) ? h2 : h3;
    int f = t & 63;
    float s = 0.f;
    for (int n = nlo; n < nhi; ++n) s += bf2f(hb[n * 64 + f]);
    ps[t] = s;
    __syncthreads();
    float acc = fc1b[t];
#pragma unroll 8
    for (int k = 0; k < 192; ++k) acc = fmaf(ps[k], fc1W[k * 192 + t], acc);
    hs[t] = fmaxf(acc, 0.f);
    __syncthreads();
    if (t == 0) {
        float l0 = fc2b[0], l1 = fc2b[1];
        for (int k = 0; k < 192; ++k) {
            float h = hs[k];
            l0 = fmaf(h, fc2W[k * 2 + 0], l0);
            l1 = fmaf(h, fc2W[k * 2 + 1], l1);
        }
        float mx = fmaxf(l0, l1);
        float lse = mx + logf(expf(l0 - mx) + expf(l1 - mx));
        out[gi * 2 + 0] = l0 - lse;
        out[gi * 2 + 1] = l1 - lse;
    }
}

extern "C" void kernel_launch(void* const* d_in, const int* in_sizes, int n_in,
                              void* d_out, int out_size, void* d_ws, size_t ws_size,
                              hipStream_t stream) {
    const float* x = (const float*)d_in[0];
    const int* src = (const int*)d_in[1];
    const int* dst = (const int*)d_in[2];
    const int* batch = (const int*)d_in[3];
    const float* c1[8];
    const float* c2[8];
    const float* c3[8];
    for (int i = 0; i < 8; ++i) {
        c1[i] = (const float*)d_in[4 + i];
        c2[i] = (const float*)d_in[12 + i];
        c3[i] = (const float*)d_in[20 + i];
    }
    const float* fc1W = (const float*)d_in[28];
    const float* fc1b = (const float*)d_in[29];
    const float* fc2W = (const float*)d_in[30];
    const float* fc2b = (const float*)d_in[31];
    float* out = (float*)d_out;

    // ---- workspace layout (all bf16 activations) ----
    unsigned short* base = (unsigned short*)d_ws;
    const size_t NA = (size_t)NNODES * 64;
    unsigned short* ybf = base;                          // N*64
    unsigned short* xbf = ybf + NA;                      // N*16
    unsigned short* h1  = xbf + (size_t)NNODES * NFP;    // N*64
    unsigned short* h2  = h1 + NA;                       // N*64
    unsigned short* h3  = h2 + NA;                       // N*64
    unsigned short* wfrag = h3 + NA;                     // 3*8192 (16B-aligned)
    int* ibase = (int*)(wfrag + 3 * 8192);
    int* cursor  = ibase;                           // N
    int* gcount  = ibase + NNODES;                  // NBUCK
    int* csr     = gcount + NBUCK;                  // N*CAP (+pad)
    int* pairbuf = csr + (size_t)NNODES * CAP + 256;  // NBUCK*RCAP

    hipMemsetAsync(gcount, 0, NBUCK * sizeof(int), stream);

    // ---- build padded CSR via 2-phase bucket partition + LDS-cursor scatter ----
    cvt_x_kernel<<<2048, 256, 0, stream>>>(x, xbf);
    build_frags_kernel<<<12, 256, 0, stream>>>(c1[0], c1[6], c2[0], c2[6], c3[0], c3[6], wfrag);
    partition_kernel<<<NPBLK, 256, 0, stream>>>(src, dst, gcount, pairbuf);
    bucket_scatter_kernel<<<NBUCK, 512, 0, stream>>>(pairbuf, gcount, cursor, csr);

    const int AGG_BLOCKS = 25000;  // 4 waves/block -> one wave per node
    const int MLP_BLOCKS = 1024;

    // ---- layer 1 (fin=13, 32 B rows): 16 edges/gather; MFMA MLP with K=32 (1 chunk) ----
    agg_vec_kernel<NFP, 4, 2, 1><<<AGG_BLOCKS, 256, 0, stream>>>(xbf, cursor, csr, ybf);
    mlp_mfma_kernel<1><<<MLP_BLOCKS, 256, 0, stream>>>(
        ybf, wfrag + 0 * 8192, c1[1], c1[2], c1[3], c1[4], c1[5], c1[7], h1);

    // ---- layer 2 (fin=64, 128 B rows): 4 edges/gather; MFMA MLP K=64 ----
    agg_vec_kernel<64, 16, 4, 0><<<AGG_BLOCKS, 256, 0, stream>>>(h1, cursor, csr, ybf);
    mlp_mfma_kernel<2><<<MLP_BLOCKS, 256, 0, stream>>>(
        ybf, wfrag + 1 * 8192, c2[1], c2[2], c2[3], c2[4], c2[5], c2[7], h2);

    // ---- layer 3 (fin=64) ----
    agg_vec_kernel<64, 16, 4, 0><<<AGG_BLOCKS, 256, 0, stream>>>(h2, cursor, csr, ybf);
    mlp_mfma_kernel<2><<<MLP_BLOCKS, 256, 0, stream>>>(
        ybf, wfrag + 2 * 8192, c3[1], c3[2], c3[3], c3[4], c3[5], c3[7], h3);

    // ---- pooling + FC head fused ----
    pool_head_kernel<<<NG, 192, 0, stream>>>(h1, h2, h3, batch, fc1W, fc1b, fc2W, fc2b, out);
}

// Round 11
// 423.582 us; speedup vs baseline: 5.3618x; 1.0677x over previous
//
#include <hip/hip_runtime.h>

#define NNODES 100000
#define NEDGES 3200000
#define NF 13
#define NFP 16       // padded bf16 row stride for x
#define NG 512
#define BN_EPS 1e-5f
#define NTILES (NNODES / 16)   // 6250 exactly
#define CAP 72       // padded CSR slots per node (deg ~ Poisson(32); P(deg>72) ~ 1e-9)

#define BSH 9                          // bucket = 512 dst nodes
#define NBUCK ((NNODES + 511) / 512)   // 196
#define RCAP 18500                     // pairs per bucket (mean 16384, sigma ~128)
#define PTILE 4096
#define NPBLK ((NEDGES + PTILE - 1) / PTILE)  // 782

#define NCHUNK ((NNODES + 63) / 64)    // 1563 64-node chunks
#define NPTASK (3 * NCHUNK)            // wave-tasks for pooling

typedef __attribute__((ext_vector_type(8))) short bf16x8;
typedef __attribute__((ext_vector_type(4))) float f32x4;

__device__ __forceinline__ float bf2f(unsigned short u) {
    return __uint_as_float(((unsigned)u) << 16);
}
__device__ __forceinline__ unsigned short f2bf(float f) {
    unsigned u = __float_as_uint(f);
    unsigned r = (u + 0x7FFFu + ((u >> 16) & 1u)) >> 16;  // RNE
    return (unsigned short)r;
}

// ---------------- phase A: partition edges into 196 buckets of 512 dst nodes ----------
__launch_bounds__(256)
__global__ void partition_kernel(const int* __restrict__ src, const int* __restrict__ dst,
                                 int* __restrict__ gcount, int* __restrict__ pairbuf) {
    __shared__ int lhist[NBUCK];
    __shared__ int lbase[NBUCK];
    __shared__ int lpos[NBUCK];
    int t = threadIdx.x;
    int base = blockIdx.x * PTILE;
    int cnt = NEDGES - base; if (cnt > PTILE) cnt = PTILE;

    int v[PTILE / 256], b[PTILE / 256];
#pragma unroll
    for (int j = 0; j < PTILE / 256; ++j) {
        int i = t + j * 256;
        if (i < cnt) {
            int d = __builtin_nontemporal_load(dst + base + i);
            int s = __builtin_nontemporal_load(src + base + i);
            b[j] = d >> BSH;
            v[j] = ((d & 511) << 17) | s;
        } else b[j] = -1;
    }
    if (t < NBUCK) lhist[t] = 0;
    __syncthreads();
#pragma unroll
    for (int j = 0; j < PTILE / 256; ++j)
        if (b[j] >= 0) atomicAdd(&lhist[b[j]], 1);
    __syncthreads();
    if (t < NBUCK) {
        lbase[t] = atomicAdd(&gcount[t], lhist[t]);
        lpos[t] = 0;
    }
    __syncthreads();
#pragma unroll
    for (int j = 0; j < PTILE / 256; ++j) {
        if (b[j] >= 0) {
            int p = atomicAdd(&lpos[b[j]], 1);
            pairbuf[(size_t)b[j] * RCAP + lbase[b[j]] + p] = v[j];
        }
    }
}

// ---------------- phase B: per-bucket scatter with LDS cursors ----------------
__launch_bounds__(512)
__global__ void bucket_scatter_kernel(const int* __restrict__ pairbuf,
                                      const int* __restrict__ gcount,
                                      int* __restrict__ cursor, int* __restrict__ csr) {
    __shared__ int lcnt[512];
    int bk = blockIdx.x;
    int lo = bk << BSH;
    int cnt = gcount[bk];
    if (threadIdx.x < 512) lcnt[threadIdx.x] = 0;
    __syncthreads();
    const int* pb = pairbuf + (size_t)bk * RCAP;
    for (int i = threadIdx.x; i < cnt; i += 512) {
        int p = pb[i];
        int s = p & 0x1FFFF;
        int dl = p >> 17;
        int pos = atomicAdd(&lcnt[dl], 1);
        csr[(size_t)(lo + dl) * CAP + pos] = s;
    }
    __syncthreads();
    int n = lo + threadIdx.x;
    if (threadIdx.x < 512 && n < NNODES) cursor[n] = n * CAP + lcnt[threadIdx.x];
}

// ---------------- convert x (fp32, stride 13) -> xbf (bf16, stride 16, zero-padded) ---
__global__ void cvt_x_kernel(const float* __restrict__ x, unsigned short* __restrict__ xbf) {
    const int total = NNODES * NFP;
    int idx = blockIdx.x * blockDim.x + threadIdx.x;
    int stride = gridDim.x * blockDim.x;
    for (int i = idx; i < total; i += stride) {
        int n = i >> 4;
        int f = i & 15;
        xbf[i] = (f < NF) ? f2bf(x[n * NF + f]) : (unsigned short)0;
    }
}

// ---------------- build MFMA B-fragments for all layer weights (bf16) ----------------
__global__ void build_frags_kernel(const float* __restrict__ w10, const float* __restrict__ w20,
                                   const float* __restrict__ w11, const float* __restrict__ w21,
                                   const float* __restrict__ w12, const float* __restrict__ w22,
                                   unsigned short* __restrict__ wfrag) {
    int tid = blockIdx.x * blockDim.x + threadIdx.x;  // 3072 total
    if (tid >= 3072) return;
    int layer = tid >> 10;
    int rem = tid & 1023;
    int mat = rem >> 9;
    int tile = (rem >> 7) & 3;
    int chunk = (rem >> 6) & 1;
    int lane = rem & 63;
    int quad = lane >> 4, n = lane & 15;
    const float* W = (layer == 0) ? (mat ? w20 : w10)
                   : (layer == 1) ? (mat ? w21 : w11)
                                  : (mat ? w22 : w12);
    int K = (layer == 0 && mat == 0) ? NF : 64;
    unsigned short* o = wfrag + ((size_t)tid) * 8;
#pragma unroll
    for (int j = 0; j < 8; ++j) {
        int k = chunk * 32 + quad * 8 + j;
        float val = (k < K) ? W[k * 64 + tile * 16 + n] : 0.f;
        o[j] = f2bf(val);
    }
}

// ---------------- vectorized bf16 aggregation (padded CSR) ----------------
template <int FSTR, int RL, int UNROLL, int PADZ>
__launch_bounds__(256, 8)
__global__ void agg_vec_kernel(const unsigned short* __restrict__ xin,
                               const int* __restrict__ cursor,
                               const int* __restrict__ csr,
                               unsigned short* __restrict__ y) {
    const int EPG = 64 / RL;
    int lane = threadIdx.x & 63;
    int g = lane / RL;
    int r = lane % RL;
    int wave = (blockIdx.x * blockDim.x + threadIdx.x) >> 6;
    int nw = (gridDim.x * blockDim.x) >> 6;

    for (int n = wave; n < NNODES; n += nw) {
        int beg = n * CAP;
        int end = cursor[n];
        float ax = 0.f, ay = 0.f, az = 0.f, aw = 0.f;
        if (g == 0) {  // self row, added once
            ushort4 u = *(const ushort4*)&xin[n * FSTR + r * 4];
            ax = bf2f(u.x); ay = bf2f(u.y); az = bf2f(u.z); aw = bf2f(u.w);
        }
        int j = beg;
        const int STEP = UNROLL * EPG;
        for (; j + STEP <= end; j += STEP) {
#pragma unroll
            for (int t = 0; t < UNROLL; ++t) {
                int e = j + t * EPG + g;           // guaranteed < end
                int i0 = csr[e];
                ushort4 u = *(const ushort4*)&xin[i0 * FSTR + r * 4];
                ax += bf2f(u.x); ay += bf2f(u.y); az += bf2f(u.z); aw += bf2f(u.w);
            }
        }
        for (; j < end; j += EPG) {
            int e = j + g;
            if (e < end) {
                int i0 = csr[e];
                ushort4 u = *(const ushort4*)&xin[i0 * FSTR + r * 4];
                ax += bf2f(u.x); ay += bf2f(u.y); az += bf2f(u.z); aw += bf2f(u.w);
            }
        }
#pragma unroll
        for (int m = RL; m < 64; m <<= 1) {
            ax += __shfl_xor(ax, m, 64);
            ay += __shfl_xor(ay, m, 64);
            az += __shfl_xor(az, m, 64);
            aw += __shfl_xor(aw, m, 64);
        }
        if (g == 0) {
            ushort4 o;
            o.x = f2bf(ax); o.y = f2bf(ay); o.z = f2bf(az); o.w = f2bf(aw);
            *(ushort4*)&y[n * 64 + r * 4] = o;
        } else if (PADZ && g == 1) {
            ushort4 o; o.x = 0; o.y = 0; o.z = 0; o.w = 0;
            *(ushort4*)&y[n * 64 + 16 + r * 4] = o;
        }
    }
}

// ---------------- MFMA MLP: 16-node tile per wave --------------------------------------
template <int KC1>
__launch_bounds__(256)
__global__ void mlp_mfma_kernel(const unsigned short* __restrict__ ybf,
                                const unsigned short* __restrict__ wfrag,
                                const float* __restrict__ b1, const float* __restrict__ g,
                                const float* __restrict__ be, const float* __restrict__ m,
                                const float* __restrict__ v,  const float* __restrict__ b2,
                                unsigned short* __restrict__ hout) {
    __shared__ __align__(16) unsigned short zs[4][16 * 72];  // per-wave slice, padded stride
    int lane = threadIdx.x & 63;
    int wid = threadIdx.x >> 6;
    int quad = lane >> 4;
    int n16 = lane & 15;

    const bf16x8* wf = (const bf16x8*)wfrag;
    bf16x8 w1f[4][2], w2f[4][2];
#pragma unroll
    for (int t = 0; t < 4; ++t) {
#pragma unroll
        for (int c = 0; c < 2; ++c) {
            w1f[t][c] = wf[((0 * 4 + t) * 2 + c) * 64 + lane];
            w2f[t][c] = wf[((1 * 4 + t) * 2 + c) * 64 + lane];
        }
    }
    float scaleF[4], shiftF[4], b2F[4];
#pragma unroll
    for (int t = 0; t < 4; ++t) {
        int f = t * 16 + n16;
        float sc = g[f] * rsqrtf(v[f] + BN_EPS);
        scaleF[t] = sc;
        shiftF[t] = (b1[f] - m[f]) * sc + be[f];
        b2F[t] = b2[f];
    }

    unsigned short* zrow = &zs[wid][0];
    int ntiles = gridDim.x * 4;
    for (int tile = blockIdx.x * 4 + wid; tile < NTILES; tile += ntiles) {
        int nodebase = tile * 16;
        const unsigned short* yrow = ybf + (size_t)(nodebase + n16) * 64 + quad * 8;
        bf16x8 a0 = *(const bf16x8*)yrow;
        bf16x8 a1 = (KC1 == 2) ? *(const bf16x8*)(yrow + 32) : a0;

        f32x4 acc[4];
#pragma unroll
        for (int t = 0; t < 4; ++t) {
            f32x4 z4 = {0.f, 0.f, 0.f, 0.f};
            z4 = __builtin_amdgcn_mfma_f32_16x16x32_bf16(a0, w1f[t][0], z4, 0, 0, 0);
            if (KC1 == 2)
                z4 = __builtin_amdgcn_mfma_f32_16x16x32_bf16(a1, w1f[t][1], z4, 0, 0, 0);
            acc[t] = z4;
        }
#pragma unroll
        for (int t = 0; t < 4; ++t) {
#pragma unroll
            for (int r = 0; r < 4; ++r) {
                float z = fmaxf(fmaf(acc[t][r], scaleF[t], shiftF[t]), 0.f);
                zrow[(quad * 4 + r) * 72 + t * 16 + n16] = f2bf(z);
            }
        }
        __threadfence_block();
        bf16x8 az0 = *(const bf16x8*)&zrow[n16 * 72 + quad * 8];
        bf16x8 az1 = *(const bf16x8*)&zrow[n16 * 72 + 32 + quad * 8];

        f32x4 acc2[4];
#pragma unroll
        for (int t = 0; t < 4; ++t) {
            f32x4 z4 = {0.f, 0.f, 0.f, 0.f};
            z4 = __builtin_amdgcn_mfma_f32_16x16x32_bf16(az0, w2f[t][0], z4, 0, 0, 0);
            z4 = __builtin_amdgcn_mfma_f32_16x16x32_bf16(az1, w2f[t][1], z4, 0, 0, 0);
            acc2[t] = z4;
        }
#pragma unroll
        for (int t = 0; t < 4; ++t) {
#pragma unroll
            for (int r = 0; r < 4; ++r) {
                float h = fmaxf(acc2[t][r] + b2F[t], 0.f);
                hout[(size_t)(nodebase + quad * 4 + r) * 64 + t * 16 + n16] = f2bf(h);
            }
        }
        __threadfence_block();
    }
}

// ---------------- pooling: one wave per (layer, 64-node chunk) ----------------
// Lane = feature. Coalesced 128 B row loads; batch id is wave-uniform so the flush
// branch is uniform; ~2 atomic flushes per wave into the 384 KB L2-resident pool.
__launch_bounds__(256)
__global__ void pool_kernel(const unsigned short* __restrict__ h1,
                            const unsigned short* __restrict__ h2,
                            const unsigned short* __restrict__ h3,
                            const int* __restrict__ batch,
                            float* __restrict__ pool) {
    int task = blockIdx.x * 4 + (threadIdx.x >> 6);
    if (task >= NPTASK) return;
    int lane = threadIdx.x & 63;
    int layer = task / NCHUNK;
    int c = task - layer * NCHUNK;
    int n0 = c * 64;
    int n1 = n0 + 64; if (n1 > NNODES) n1 = NNODES;
    const unsigned short* hb = (layer == 0) ? h1 : (layer == 1) ? h2 : h3;
    float acc = 0.f;
    int curg = batch[n0];
    for (int n = n0; n < n1; ++n) {
        int gid = batch[n];
        if (gid != curg) {
            atomicAdd(&pool[(size_t)curg * 192 + layer * 64 + lane], acc);
            acc = 0.f;
            curg = gid;
        }
        acc += bf2f(hb[(size_t)n * 64 + lane]);
    }
    atomicAdd(&pool[(size_t)curg * 192 + layer * 64 + lane], acc);
}

// ---------------- FC head on pooled features: relu(p@fc1W+b)@fc2W+b, log_softmax ------
__global__ void head_kernel(const float* __restrict__ pool,
                            const float* __restrict__ fc1W, const float* __restrict__ fc1b,
                            const float* __restrict__ fc2W, const float* __restrict__ fc2b,
                            float* __restrict__ out) {
    __shared__ float ps[192];
    __shared__ float hs[192];
    int gi = blockIdx.x;
    int t = threadIdx.x;  // 192
    ps[t] = pool[gi * 192 + t];
    __syncthreads();
    float acc = fc1b[t];
#pragma unroll 8
    for (int k = 0; k < 192; ++k) acc = fmaf(ps[k], fc1W[k * 192 + t], acc);
    hs[t] = fmaxf(acc, 0.f);
    __syncthreads();
    if (t == 0) {
        float l0 = fc2b[0], l1 = fc2b[1];
        for (int k = 0; k < 192; ++k) {
            float h = hs[k];
            l0 = fmaf(h, fc2W[k * 2 + 0], l0);
            l1 = fmaf(h, fc2W[k * 2 + 1], l1);
        }
        float mx = fmaxf(l0, l1);
        float lse = mx + logf(expf(l0 - mx) + expf(l1 - mx));
        out[gi * 2 + 0] = l0 - lse;
        out[gi * 2 + 1] = l1 - lse;
    }
}

extern "C" void kernel_launch(void* const* d_in, const int* in_sizes, int n_in,
                              void* d_out, int out_size, void* d_ws, size_t ws_size,
                              hipStream_t stream) {
    const float* x = (const float*)d_in[0];
    const int* src = (const int*)d_in[1];
    const int* dst = (const int*)d_in[2];
    const int* batch = (const int*)d_in[3];
    const float* c1[8];
    const float* c2[8];
    const float* c3[8];
    for (int i = 0; i < 8; ++i) {
        c1[i] = (const float*)d_in[4 + i];
        c2[i] = (const float*)d_in[12 + i];
        c3[i] = (const float*)d_in[20 + i];
    }
    const float* fc1W = (const float*)d_in[28];
    const float* fc1b = (const float*)d_in[29];
    const float* fc2W = (const float*)d_in[30];
    const float* fc2b = (const float*)d_in[31];
    float* out = (float*)d_out;

    // ---- workspace layout (all bf16 activations) ----
    unsigned short* base = (unsigned short*)d_ws;
    const size_t NA = (size_t)NNODES * 64;
    unsigned short* ybf = base;                          // N*64
    unsigned short* xbf = ybf + NA;                      // N*16
    unsigned short* h1  = xbf + (size_t)NNODES * NFP;    // N*64
    unsigned short* h2  = h1 + NA;                       // N*64
    unsigned short* h3  = h2 + NA;                       // N*64
    unsigned short* wfrag = h3 + NA;                     // 3*8192 (16B-aligned)
    float* pool = (float*)(wfrag + 3 * 8192);            // G*192 fp32
    int* ibase = (int*)(pool + (size_t)NG * 192);
    int* cursor  = ibase;                           // N
    int* gcount  = ibase + NNODES;                  // NBUCK
    int* csr     = gcount + NBUCK;                  // N*CAP (+pad)
    int* pairbuf = csr + (size_t)NNODES * CAP + 256;  // NBUCK*RCAP

    hipMemsetAsync(gcount, 0, NBUCK * sizeof(int), stream);
    hipMemsetAsync(pool, 0, (size_t)NG * 192 * sizeof(float), stream);

    // ---- build padded CSR via 2-phase bucket partition + LDS-cursor scatter ----
    cvt_x_kernel<<<2048, 256, 0, stream>>>(x, xbf);
    build_frags_kernel<<<12, 256, 0, stream>>>(c1[0], c1[6], c2[0], c2[6], c3[0], c3[6], wfrag);
    partition_kernel<<<NPBLK, 256, 0, stream>>>(src, dst, gcount, pairbuf);
    bucket_scatter_kernel<<<NBUCK, 512, 0, stream>>>(pairbuf, gcount, cursor, csr);

    const int AGG_BLOCKS = 25000;  // 4 waves/block -> one wave per node
    const int MLP_BLOCKS = 1024;

    // ---- layer 1 (fin=13, 32 B rows): 16 edges/gather; MFMA MLP with K=32 (1 chunk) ----
    agg_vec_kernel<NFP, 4, 2, 1><<<AGG_BLOCKS, 256, 0, stream>>>(xbf, cursor, csr, ybf);
    mlp_mfma_kernel<1><<<MLP_BLOCKS, 256, 0, stream>>>(
        ybf, wfrag + 0 * 8192, c1[1], c1[2], c1[3], c1[4], c1[5], c1[7], h1);

    // ---- layer 2 (fin=64, 128 B rows): 4 edges/gather; MFMA MLP K=64 ----
    agg_vec_kernel<64, 16, 4, 0><<<AGG_BLOCKS, 256, 0, stream>>>(h1, cursor, csr, ybf);
    mlp_mfma_kernel<2><<<MLP_BLOCKS, 256, 0, stream>>>(
        ybf, wfrag + 1 * 8192, c2[1], c2[2], c2[3], c2[4], c2[5], c2[7], h2);

    // ---- layer 3 (fin=64) ----
    agg_vec_kernel<64, 16, 4, 0><<<AGG_BLOCKS, 256, 0, stream>>>(h2, cursor, csr, ybf);
    mlp_mfma_kernel<2><<<MLP_BLOCKS, 256, 0, stream>>>(
        ybf, wfrag + 2 * 8192, c3[1], c3[2], c3[3], c3[4], c3[5], c3[7], h3);

    // ---- pooling (one wave per layer-chunk) + FC head ----
    pool_kernel<<<(NPTASK + 3) / 4, 256, 0, stream>>>(h1, h2, h3, batch, pool);
    head_kernel<<<NG, 192, 0, stream>>>(pool, fc1W, fc1b, fc2W, fc2b, out);
}